// Round 7
// baseline (323.776 us; speedup 1.0000x reference)
//
#include <hip/hip_runtime.h>
#include <hip/hip_bf16.h>
#include <stdint.h>

// Problem constants
#define BB 4
#define TT 2048
#define DD 1024
#define HH 16
#define HDD 64
// derived
#define M1 (BB*TT)      // 8192 rows
#define N1 (3*DD)       // 3072
#define KDIM DD         // 1024

typedef __attribute__((ext_vector_type(8))) short short8;   // 8 bf16 MFMA operand
typedef __attribute__((ext_vector_type(4))) float f32x4;

#if __has_builtin(__builtin_amdgcn_exp2f)
#define EXP2(x) __builtin_amdgcn_exp2f(x)
#else
#define EXP2(x) exp2f(x)
#endif

// async global->LDS, 16B per lane (global_load_lds_dwordx4)
#define GLOAD_LDS16(gp, lp) \
    __builtin_amdgcn_global_load_lds( \
        (const __attribute__((address_space(1))) void*)(gp), \
        (__attribute__((address_space(3))) void*)(lp), 16, 0, 0)

__device__ __forceinline__ float bf2f(unsigned short u) {
    union { uint32_t u32; float f; } c; c.u32 = ((uint32_t)u) << 16; return c.f;
}
__device__ __forceinline__ unsigned short f2bf(float f) {
    union { float f; uint32_t u32; } c; c.f = f;
    uint32_t u = c.u32;
    return (unsigned short)((u + 0x7FFFu + ((u >> 16) & 1u)) >> 16);  // RNE
}

// DPP row_ror rotate-reduce within the 16-lane DPP row.
template <int CTRL>
__device__ __forceinline__ float dpp_ror(float x) {
    union { float f; int i; } u, r;
    u.f = x;
    r.i = __builtin_amdgcn_update_dpp(u.i, u.i, CTRL, 0xF, 0xF, false);
    return r.f;
}
__device__ __forceinline__ float red_max16(float x) {
    x = fmaxf(x, dpp_ror<0x128>(x));   // row_ror:8
    x = fmaxf(x, dpp_ror<0x124>(x));   // row_ror:4
    x = fmaxf(x, dpp_ror<0x122>(x));   // row_ror:2
    x = fmaxf(x, dpp_ror<0x121>(x));   // row_ror:1
    return x;
}
__device__ __forceinline__ float red_sum16(float x) {
    x += dpp_ror<0x128>(x);
    x += dpp_ror<0x124>(x);
    x += dpp_ror<0x122>(x);
    x += dpp_ror<0x121>(x);
    return x;
}

// ---------------- elementwise fp32 -> bf16 (x), 4 elems/thread ----------------
__global__ __launch_bounds__(256) void cvt_f32_bf16(
    const float* __restrict__ in, unsigned short* __restrict__ out, int n4)
{
    int i = blockIdx.x * 256 + threadIdx.x;
    if (i >= n4) return;
    float4 v = *(const float4*)&in[(size_t)i * 4];
    ushort4 o;
    o.x = f2bf(v.x); o.y = f2bf(v.y); o.z = f2bf(v.z); o.w = f2bf(v.w);
    *(ushort4*)&out[(size_t)i * 4] = o;
}

// ---------------- transpose+convert: in fp32 [R][C] -> out bf16 [C][R] ----------------
__global__ __launch_bounds__(256) void transpose_f32_bf16(
    const float* __restrict__ in, unsigned short* __restrict__ out,
    int R, int C)
{
    __shared__ unsigned short tile[32][33];
    int bx = blockIdx.x;
    int by = blockIdx.y;
    int x = bx*32 + threadIdx.x;
    int y0 = by*32 + threadIdx.y;
    #pragma unroll
    for (int i = 0; i < 32; i += 8)
        tile[threadIdx.y + i][threadIdx.x] = f2bf(in[(size_t)(y0 + i)*C + x]);
    __syncthreads();
    int xo = by*32 + threadIdx.x;
    int yo = bx*32 + threadIdx.y;
    #pragma unroll
    for (int i = 0; i < 32; i += 8)
        out[(size_t)(yo + i)*R + xo] = tile[threadIdx.x][threadIdx.y + i];
}

// ---------------- big-tile MFMA bf16 GEMM, m201-style per-phase interleave ------
// Round-6 post-mortem: exact grids gained 20us, but the GEMMs still run ~420 TF.
// Cause (m196/m233 regime): lockstep 12x ds_read bursts + stage clustered at
// tile end = the "2-phase" losing variant. This round ports the verified
// 8-phase interleave onto the exact-fit tiles:
//  - TRIPLE-buffered LDS (3 x (BM+BN)*64 shorts = 144 KB). stage(t+2) is
//    issued INSIDE tile t's phases (parts 2/2/1/1) -> at tile top vmcnt(6)
//    leaves stage(t+1)'s 6 loads in flight across the barrier (T4 counted).
//    Last 2 tiles: vmcnt(0) at t==nk-1 (no newer stage in flight -> must drain).
//  - 4 phases/tile over C-quadrants (0,0),(0,1),(1,1),(1,0) with fragment
//    reuse (fa0/fa1/fb0/fb1 live as needed): each phase =
//    {ds_read subtile ∥ stage part -> s_barrier -> setprio(1) 8 MFMA
//     setprio(0) -> s_barrier}  (m201 phase skeleton).
//  - T2 swizzle: chunk ^= row&7 on stage SOURCE + same XOR on ds_read_b128.
//  - Race-freedom: RAW = per-wave vmcnt BEFORE barrier (all waves' stage
//    portions landed once every wave passed its own vmcnt); WAR = stage(t+2)
//    targets buf[(t-1)%3], whose reads retired before tile t's top barrier.
// Grids stay exact-fit: QKV BM=256xBN=128 -> 768 = 3/CU rounds; out-proj
// BM=128xBN=256 -> 256 = 1/CU. XCD-chunked bid swizzle (both %8==0).
// MODE 1: f32 C[M][N].  MODE 2: n0<2048 -> bf16 QK; n0>=2048 -> V^T epilogue.
template <int MODE, int BM, int BN>
__global__ __launch_bounds__(512, 2) void gemm_big(
    const unsigned short* __restrict__ A, const unsigned short* __restrict__ BT,
    const float* __restrict__ bias, void* __restrict__ Cout, void* __restrict__ Cout2,
    int K, int N, int NXT)
{
    constexpr int TBUF = (BM + BN) * 64;             // shorts per K-tile buffer
    constexpr int NPART = (BM + BN) / 64;            // 6 stage loads per tile
    __shared__ __align__(16) unsigned short Sh[3 * TBUF];   // 144 KB

    const int tid  = threadIdx.x;
    const int lane = tid & 63;
    const int wave = tid >> 6;                       // 0..7
    constexpr int WNG = BN / 64;                     // waves along n
    const int wm = wave / WNG, wn = wave % WNG;
    const int quad = lane >> 4, l16 = lane & 15;

    // XCD-chunked swizzle: each XCD gets a contiguous wg range (A-panel reuse)
    const int nwg = gridDim.x, cpx = nwg >> 3;
    const int wg = (blockIdx.x & 7)*cpx + (blockIdx.x >> 3);
    const int by = wg / NXT, bx = wg - by*NXT;
    const int m0 = by*BM, n0 = bx*BN;

    f32x4 acc[4][4] = {};
    const int nk = K >> 6;

    // stage one 8KB part of tile tt into buffer bufi (part is a literal ->
    // the A/B branch folds at compile time)
    auto STAGE_PART = [&](int tt, int bufi, int part) {
        const int k0 = tt << 6;
        unsigned short* base = &Sh[bufi * TBUF];
        if ((part + 1) * 512 <= BM * 8) {
            int c = part*512 + tid;
            int row = c >> 3, ch = (c & 7) ^ (row & 7);
            GLOAD_LDS16(&A[(size_t)(m0 + row)*K + k0 + ch*8], &base[c*8]);
        } else {
            int c = part*512 + tid - BM*8;
            int row = c >> 3, ch = (c & 7) ^ (row & 7);
            GLOAD_LDS16(&BT[(size_t)(n0 + row)*K + k0 + ch*8], &base[BM*64 + c*8]);
        }
    };

    #pragma unroll
    for (int p = 0; p < NPART; ++p) STAGE_PART(0, 0, p);
    #pragma unroll
    for (int p = 0; p < NPART; ++p) STAGE_PART(1, 1, p);

    int bR = 0;                                      // buffer holding tile t
    for (int t = 0; t < nk; ++t) {
        const unsigned short* Ab = &Sh[bR * TBUF];
        const unsigned short* Bb = &Sh[bR * TBUF + BM*64];
        const int bS = (bR + 2 >= 3) ? bR - 1 : bR + 2;   // (t+2)%3
        const bool pf = (t + 2 < nk);

        if (t >= nk - 1) asm volatile("s_waitcnt vmcnt(0)" ::: "memory");
        else             asm volatile("s_waitcnt vmcnt(6)" ::: "memory");
        __builtin_amdgcn_s_barrier();
        __builtin_amdgcn_sched_barrier(0);           // no ds_read hoists above

        short8 fa0[2][2], fa1[2][2], fb0[2][2], fb1[2][2];

        // ---- phase 0: quadrant (m-lo, n-lo)
        #pragma unroll
        for (int i = 0; i < 2; ++i)
            #pragma unroll
            for (int kk = 0; kk < 2; ++kk) {
                int row = wm*64 + i*16 + l16;
                fa0[i][kk] = *(const short8*)&Ab[row*64 + (((kk*4 + quad) ^ (row & 7))*8)];
            }
        #pragma unroll
        for (int j = 0; j < 2; ++j)
            #pragma unroll
            for (int kk = 0; kk < 2; ++kk) {
                int row = wn*64 + j*16 + l16;
                fb0[j][kk] = *(const short8*)&Bb[row*64 + (((kk*4 + quad) ^ (row & 7))*8)];
            }
        if (pf) { STAGE_PART(t+2, bS, 0); STAGE_PART(t+2, bS, 1); }
        __builtin_amdgcn_s_barrier();
        __builtin_amdgcn_s_setprio(1);
        #pragma unroll
        for (int i = 0; i < 2; ++i)
            #pragma unroll
            for (int j = 0; j < 2; ++j)
                #pragma unroll
                for (int kk = 0; kk < 2; ++kk)
                    acc[i][j] = __builtin_amdgcn_mfma_f32_16x16x32_bf16(
                        fa0[i][kk], fb0[j][kk], acc[i][j], 0, 0, 0);
        __builtin_amdgcn_s_setprio(0);
        __builtin_amdgcn_s_barrier();

        // ---- phase 1: quadrant (m-lo, n-hi)
        #pragma unroll
        for (int j = 0; j < 2; ++j)
            #pragma unroll
            for (int kk = 0; kk < 2; ++kk) {
                int row = wn*64 + 32 + j*16 + l16;
                fb1[j][kk] = *(const short8*)&Bb[row*64 + (((kk*4 + quad) ^ (row & 7))*8)];
            }
        if (pf) { STAGE_PART(t+2, bS, 2); STAGE_PART(t+2, bS, 3); }
        __builtin_amdgcn_s_barrier();
        __builtin_amdgcn_s_setprio(1);
        #pragma unroll
        for (int i = 0; i < 2; ++i)
            #pragma unroll
            for (int j = 0; j < 2; ++j)
                #pragma unroll
                for (int kk = 0; kk < 2; ++kk)
                    acc[i][2+j] = __builtin_amdgcn_mfma_f32_16x16x32_bf16(
                        fa0[i][kk], fb1[j][kk], acc[i][2+j], 0, 0, 0);
        __builtin_amdgcn_s_setprio(0);
        __builtin_amdgcn_s_barrier();

        // ---- phase 2: quadrant (m-hi, n-hi)
        #pragma unroll
        for (int i = 0; i < 2; ++i)
            #pragma unroll
            for (int kk = 0; kk < 2; ++kk) {
                int row = wm*64 + 32 + i*16 + l16;
                fa1[i][kk] = *(const short8*)&Ab[row*64 + (((kk*4 + quad) ^ (row & 7))*8)];
            }
        if (pf) STAGE_PART(t+2, bS, 4);
        __builtin_amdgcn_s_barrier();
        __builtin_amdgcn_s_setprio(1);
        #pragma unroll
        for (int i = 0; i < 2; ++i)
            #pragma unroll
            for (int j = 0; j < 2; ++j)
                #pragma unroll
                for (int kk = 0; kk < 2; ++kk)
                    acc[2+i][2+j] = __builtin_amdgcn_mfma_f32_16x16x32_bf16(
                        fa1[i][kk], fb1[j][kk], acc[2+i][2+j], 0, 0, 0);
        __builtin_amdgcn_s_setprio(0);
        __builtin_amdgcn_s_barrier();

        // ---- phase 3: quadrant (m-hi, n-lo) — reuses fa1, fb0 (no reads)
        if (pf) STAGE_PART(t+2, bS, 5);
        __builtin_amdgcn_s_barrier();
        __builtin_amdgcn_s_setprio(1);
        #pragma unroll
        for (int i = 0; i < 2; ++i)
            #pragma unroll
            for (int j = 0; j < 2; ++j)
                #pragma unroll
                for (int kk = 0; kk < 2; ++kk)
                    acc[2+i][j] = __builtin_amdgcn_mfma_f32_16x16x32_bf16(
                        fa1[i][kk], fb0[j][kk], acc[2+i][j], 0, 0, 0);
        __builtin_amdgcn_s_setprio(0);
        __builtin_amdgcn_s_barrier();

        bR = (bR + 1 >= 3) ? 0 : bR + 1;
    }

    if (MODE == 2 && n0 >= 2048) {
        // V third: transpose via LDS (all staging landed: t=nk-1 waited vmcnt(0);
        // all reads retired: final phase barrier)
        constexpr int STR = BM + 8;
        #pragma unroll
        for (int ni = 0; ni < 4; ++ni) {
            int nl = wn*64 + ni*16 + l16;            // local n 0..BN-1
            float bv = bias[n0 + nl];
            #pragma unroll
            for (int mi = 0; mi < 4; ++mi) {
                ushort4 pk;
                pk.x = f2bf(acc[mi][ni][0] + bv);
                pk.y = f2bf(acc[mi][ni][1] + bv);
                pk.z = f2bf(acc[mi][ni][2] + bv);
                pk.w = f2bf(acc[mi][ni][3] + bv);
                *(ushort4*)&Sh[nl*STR + wm*64 + mi*16 + quad*4] = pk;
            }
        }
        __builtin_amdgcn_s_barrier();
        const int bb = m0 >> 11, t0 = m0 & 2047;
        constexpr int CHROW = BM/8;                  // 16B chunks per n-row
        constexpr int NIT = BN*CHROW/512;
        #pragma unroll
        for (int p = 0; p < NIT; ++p) {
            int c = p*512 + tid;
            int row = c / CHROW, ch = c % CHROW;     // row: local n
            int nv = n0 + row - 2048;
            int hv = nv >> 6, dv = nv & 63;
            *(uint4*)&((unsigned short*)Cout2)[((size_t)((bb*16 + hv)*64 + dv))*2048 + t0 + ch*8] =
                *(uint4*)&Sh[row*STR + ch*8];
        }
        return;
    }

    const int cstride = (MODE == 2) ? 2048 : N;
    #pragma unroll
    for (int ni = 0; ni < 4; ++ni) {
        int n = n0 + wn*64 + ni*16 + l16;
        float bv = bias[n];
        #pragma unroll
        for (int mi = 0; mi < 4; ++mi) {
            #pragma unroll
            for (int r = 0; r < 4; ++r) {
                int m = m0 + wm*64 + mi*16 + quad*4 + r;
                float val = acc[mi][ni][r] + bv;
                if (MODE == 1)
                    ((float*)Cout)[(size_t)m*cstride + n] = val;
                else
                    ((unsigned short*)Cout)[(size_t)m*cstride + n] = f2bf(val);
            }
        }
    }
}

// ---------------- MFMA flash attention: 4-wave block, LDS K+V, paired q-chunks ----
// (unchanged from round 4: best measured 122us. Uniform 34 k-tiles/block via
// complementary q-chunk pair (a, 15-a); K/V LDS dbuf, 2-phase pipeline, DPP
// softmax; XCD pinning i&7.)
#define PST 72
__global__ __launch_bounds__(256, 3) void attn_mfma(
    const unsigned short* __restrict__ QK, const unsigned short* __restrict__ VT,
    unsigned short* __restrict__ Y)
{
    // LDS: K dbuf 2x4096 shorts, V dbuf 2x4096 shorts, P 4 waves x 32 x PST
    __shared__ __align__(16) unsigned short Sh[16384 + 4*32*PST];

    const int tid  = threadIdx.x;
    const int lane = tid & 63;
    const int wave = tid >> 6;
    const int quad = lane >> 4, l16 = lane & 15;

    const int i = blockIdx.x;            // 0..511
    const int xcd = i & 7, j = i >> 3;   // j 0..63
    const int a = j & 7;                 // chunk-pair index: handles qc=a then 15-a
    const int u = j >> 3;                // bh-group 0..7
    const int bh2 = xcd + 8*u;
    const int b = bh2 >> 4, h = bh2 & 15;
    const size_t qkbase = (size_t)(b*TT) * 2048;
    const size_t vbase  = (size_t)(bh2*64) * 2048;
    const int qcol = h*64, kcol = 1024 + h*64;
    const float C2 = 0.18033688011112042f;   // (1/sqrt(64)) * log2(e)

    unsigned short* Pw = &Sh[16384 + wave*(32*PST)];

    const int nk1 = 2*a + 2;             // pass-0 tile count (qc = a)
    const int ntot = 34;                 // uniform for all blocks

    short8 aq[2][2];
    f32x4 o[2][4];
    float mold[2][4], lsum[2][4];
    int q0w = a*128 + wave*32;           // current pass q-row base for this wave

    auto LOADQ = [&]() {
        #pragma unroll
        for (int mt = 0; mt < 2; ++mt)
            #pragma unroll
            for (int kk = 0; kk < 2; ++kk)
                aq[mt][kk] = *(const short8*)&QK[qkbase + (size_t)(q0w + mt*16 + l16)*2048
                                                + qcol + kk*32 + quad*8];
        #pragma unroll
        for (int mt = 0; mt < 2; ++mt)
            #pragma unroll
            for (int r = 0; r < 4; ++r) { mold[mt][r] = -3.0e38f; lsum[mt][r] = 0.0f; }
        #pragma unroll
        for (int mt = 0; mt < 2; ++mt)
            #pragma unroll
            for (int dt = 0; dt < 4; ++dt) { f32x4 z = {}; o[mt][dt] = z; }
    };
    auto FINALIZE = [&]() {
        #pragma unroll
        for (int mt = 0; mt < 2; ++mt)
            #pragma unroll
            for (int r = 0; r < 4; ++r) {
                float inv = 1.0f / lsum[mt][r];
                int tq = q0w + mt*16 + quad*4 + r;
                #pragma unroll
                for (int dt = 0; dt < 4; ++dt)
                    Y[((size_t)(b*TT + tq))*DD + h*64 + dt*16 + l16] = f2bf(o[mt][dt][r] * inv);
            }
    };

    auto STAGE = [&](int buf, int k0) {
        unsigned short* Kb = &Sh[buf*4096];
        unsigned short* Vb = &Sh[8192 + buf*4096];
        #pragma unroll
        for (int p = 0; p < 2; ++p) {
            int c = p*256 + tid;               // 16B chunk index, linear in lane
            int r = c >> 3;
            int ch = (c & 7) ^ (r & 7);        // source chunk (inverse swizzle)
            GLOAD_LDS16(&QK[qkbase + (size_t)(k0 + r)*2048 + kcol + ch*8], &Kb[c*8]);
        }
        #pragma unroll
        for (int p = 0; p < 2; ++p) {
            int c = p*256 + tid;
            int r = c >> 3;                    // r = head-dim row of VT
            int ch = (c & 7) ^ (r & 7);
            GLOAD_LDS16(&VT[vbase + (size_t)r*2048 + k0 + ch*8], &Vb[c*8]);
        }
    };

    LOADQ();
    STAGE(0, 0);
    asm volatile("s_waitcnt vmcnt(0)" ::: "memory");
    __builtin_amdgcn_s_barrier();

    int cur = 0;
    for (int t = 0; t < ntot; ++t) {
        const int k0 = ((t < nk1) ? t : t - nk1) * 64;
        if (t + 1 < ntot) {
            const int t1 = t + 1;
            STAGE(cur ^ 1, ((t1 < nk1) ? t1 : t1 - nk1) * 64);   // async prefetch
        }
        if (t == nk1) {
            FINALIZE();
            q0w = (15 - a)*128 + wave*32;
            LOADQ();
        }

        if (k0 <= q0w + 31) {                  // wave-uniform causal activity guard
            const unsigned short* Kb = &Sh[cur*4096];
            const unsigned short* Vb = &Sh[8192 + cur*4096];

            // ---- S = Q K^T from LDS (swizzled reads)
            f32x4 s[2][4];
            #pragma unroll
            for (int nt = 0; nt < 4; ++nt) {
                if (k0 + nt*16 <= q0w + 31) {
                    f32x4 z = {};
                    s[0][nt] = z; s[1][nt] = z;
                    #pragma unroll
                    for (int kk = 0; kk < 2; ++kk) {
                        int r = nt*16 + l16;
                        short8 bk = *(const short8*)&Kb[r*64 + (((kk*4 + quad) ^ (r & 7))*8)];
                        s[0][nt] = __builtin_amdgcn_mfma_f32_16x16x32_bf16(aq[0][kk], bk, s[0][nt], 0, 0, 0);
                        s[1][nt] = __builtin_amdgcn_mfma_f32_16x16x32_bf16(aq[1][kk], bk, s[1][nt], 0, 0, 0);
                    }
                } else {
                    #pragma unroll
                    for (int r = 0; r < 4; ++r) { s[0][nt][r] = -3.0e38f; s[1][nt][r] = -3.0e38f; }
                }
            }

            // ---- issue V-frag LDS loads now; latency hides under softmax
            short8 bv[2][4];
            #pragma unroll
            for (int kk = 0; kk < 2; ++kk)
                #pragma unroll
                for (int dt = 0; dt < 4; ++dt) {
                    int r = dt*16 + l16;
                    bv[kk][dt] = *(const short8*)&Vb[r*64 + (((kk*4 + quad) ^ (r & 7))*8)];
                }

            // ---- element causal mask (straddling tiles only)
            if (k0 + 63 > q0w) {
                #pragma unroll
                for (int mt = 0; mt < 2; ++mt)
                    #pragma unroll
                    for (int nt = 0; nt < 4; ++nt)
                        #pragma unroll
                        for (int r = 0; r < 4; ++r) {
                            int kg = k0 + nt*16 + l16;
                            int qg = q0w + mt*16 + quad*4 + r;
                            if (kg > qg) s[mt][nt][r] = -3.0e38f;
                        }
            }

            // ---- online softmax (exp2 domain), DPP reductions
            float m2n[2][4], al[2][4];
            #pragma unroll
            for (int mt = 0; mt < 2; ++mt)
                #pragma unroll
                for (int r = 0; r < 4; ++r) {
                    float rm = fmaxf(fmaxf(s[mt][0][r], s[mt][1][r]),
                                     fmaxf(s[mt][2][r], s[mt][3][r]));
                    rm = red_max16(rm);
                    float m2 = fmaxf(mold[mt][r], rm * C2);
                    al[mt][r]  = EXP2(mold[mt][r] - m2);
                    m2n[mt][r] = m2;
                }
            float rs[2][4] = {};
            #pragma unroll
            for (int mt = 0; mt < 2; ++mt)
                #pragma unroll
                for (int nt = 0; nt < 4; ++nt)
                    #pragma unroll
                    for (int r = 0; r < 4; ++r) {
                        float p = EXP2(fmaf(s[mt][nt][r], C2, -m2n[mt][r]));
                        s[mt][nt][r] = p;
                        rs[mt][r] += p;
                    }
            #pragma unroll
            for (int mt = 0; mt < 2; ++mt)
                #pragma unroll
                for (int r = 0; r < 4; ++r) {
                    float tsum = red_sum16(rs[mt][r]);
                    lsum[mt][r] = lsum[mt][r]*al[mt][r] + tsum;
                    mold[mt][r] = m2n[mt][r];
                }

            // ---- P -> LDS (wave-private buffer; same-wave RAW, no barrier)
            #pragma unroll
            for (int mt = 0; mt < 2; ++mt)
                #pragma unroll
                for (int nt = 0; nt < 4; ++nt)
                    #pragma unroll
                    for (int r = 0; r < 4; ++r) {
                        union { float f; uint32_t u; } c; c.f = s[mt][nt][r];
                        Pw[(mt*16 + quad*4 + r)*PST + nt*16 + l16] =
                            (unsigned short)((c.u + 0x8000u) >> 16);
                    }

            // ---- O = O*alpha + P V
            #pragma unroll
            for (int mt = 0; mt < 2; ++mt)
                #pragma unroll
                for (int dt = 0; dt < 4; ++dt)
                    #pragma unroll
                    for (int r = 0; r < 4; ++r)
                        o[mt][dt][r] *= al[mt][r];
            #pragma unroll
            for (int kk = 0; kk < 2; ++kk) {
                short8 ap0 = *(short8*)&Pw[(     l16)*PST + kk*32 + quad*8];
                short8 ap1 = *(short8*)&Pw[(16 + l16)*PST + kk*32 + quad*8];
                #pragma unroll
                for (int dt = 0; dt < 4; ++dt) {
                    o[0][dt] = __builtin_amdgcn_mfma_f32_16x16x32_bf16(ap0, bv[kk][dt], o[0][dt], 0, 0, 0);
                    o[1][dt] = __builtin_amdgcn_mfma_f32_16x16x32_bf16(ap1, bv[kk][dt], o[1][dt], 0, 0, 0);
                }
            }
        }

        asm volatile("s_waitcnt vmcnt(0)" ::: "memory");  // next-tile stage landed
        __builtin_amdgcn_s_barrier();                     // all waves' stage + reads done
        cur ^= 1;
    }

    FINALIZE();   // pass-1 (chunk 15-a) output
}

extern "C" void kernel_launch(void* const* d_in, const int* in_sizes, int n_in,
                              void* d_out, int out_size, void* d_ws, size_t ws_size,
                              hipStream_t stream)
{
    const float* x    = (const float*)d_in[0];   // [4,2048,1024] fp32
    // d_in[1] = causal_mask (int32) — causality implemented analytically, unused
    const float* wqkv = (const float*)d_in[2];   // [1024][3072] fp32
    const float* bqkv = (const float*)d_in[3];   // [3072] fp32
    const float* wout = (const float*)d_in[4];   // [1024][1024] fp32
    const float* bout = (const float*)d_in[5];   // [1024] fp32
    float* out = (float*)d_out;                  // [4,2048,1024] fp32

    char* ws = (char*)d_ws;
    unsigned short* Xb    = (unsigned short*)ws;                    // 16 MB
    unsigned short* WqkvT = (unsigned short*)(ws + 16777216);       // 6 MB
    unsigned short* WoutT = (unsigned short*)(ws + 23068672);       // 2 MB
    unsigned short* QK    = (unsigned short*)(ws + 25165824);       // 32 MB [M][2048]
    unsigned short* VTb   = (unsigned short*)(ws + 58720256);       // 16 MB [(bh*64+d)][2048]
    unsigned short* Ybuf  = (unsigned short*)(ws + 75497472);       // 16 MB

    cvt_f32_bf16<<<(M1*KDIM/4 + 255)/256, 256, 0, stream>>>(x, Xb, M1*KDIM/4);
    transpose_f32_bf16<<<dim3(N1/32, KDIM/32), dim3(32, 8), 0, stream>>>(wqkv, WqkvT, KDIM, N1);
    transpose_f32_bf16<<<dim3(DD/32, KDIM/32), dim3(32, 8), 0, stream>>>(wout, WoutT, KDIM, DD);
    gemm_big<2, 256, 128><<<dim3(768), 512, 0, stream>>>(Xb, WqkvT, bqkv, QK, VTb, KDIM, N1, 24);
    attn_mfma<<<dim3(512), 256, 0, stream>>>(QK, VTb, Ybuf);
    gemm_big<1, 128, 256><<<dim3(256), 512, 0, stream>>>(Ybuf, WoutT, bout, out, nullptr, KDIM, DD, 4);
}

// Round 8
// 312.338 us; speedup vs baseline: 1.0366x; 1.0366x over previous
//
#include <hip/hip_runtime.h>
#include <hip/hip_bf16.h>
#include <stdint.h>

// Problem constants
#define BB 4
#define TT 2048
#define DD 1024
#define HH 16
#define HDD 64
// derived
#define M1 (BB*TT)      // 8192 rows
#define N1 (3*DD)       // 3072
#define KDIM DD         // 1024

typedef __attribute__((ext_vector_type(8))) short short8;   // 8 bf16 MFMA operand
typedef __attribute__((ext_vector_type(4))) float f32x4;

#if __has_builtin(__builtin_amdgcn_exp2f)
#define EXP2(x) __builtin_amdgcn_exp2f(x)
#else
#define EXP2(x) exp2f(x)
#endif

// async global->LDS, 16B per lane (global_load_lds_dwordx4)
#define GLOAD_LDS16(gp, lp) \
    __builtin_amdgcn_global_load_lds( \
        (const __attribute__((address_space(1))) void*)(gp), \
        (__attribute__((address_space(3))) void*)(lp), 16, 0, 0)

__device__ __forceinline__ float bf2f(unsigned short u) {
    union { uint32_t u32; float f; } c; c.u32 = ((uint32_t)u) << 16; return c.f;
}
__device__ __forceinline__ unsigned short f2bf(float f) {
    union { float f; uint32_t u32; } c; c.f = f;
    uint32_t u = c.u32;
    return (unsigned short)((u + 0x7FFFu + ((u >> 16) & 1u)) >> 16);  // RNE
}

// DPP row_ror rotate-reduce within the 16-lane DPP row.
template <int CTRL>
__device__ __forceinline__ float dpp_ror(float x) {
    union { float f; int i; } u, r;
    u.f = x;
    r.i = __builtin_amdgcn_update_dpp(u.i, u.i, CTRL, 0xF, 0xF, false);
    return r.f;
}
__device__ __forceinline__ float red_max16(float x) {
    x = fmaxf(x, dpp_ror<0x128>(x));   // row_ror:8
    x = fmaxf(x, dpp_ror<0x124>(x));   // row_ror:4
    x = fmaxf(x, dpp_ror<0x122>(x));   // row_ror:2
    x = fmaxf(x, dpp_ror<0x121>(x));   // row_ror:1
    return x;
}
__device__ __forceinline__ float red_sum16(float x) {
    x += dpp_ror<0x128>(x);
    x += dpp_ror<0x124>(x);
    x += dpp_ror<0x122>(x);
    x += dpp_ror<0x121>(x);
    return x;
}

// ---------------- elementwise fp32 -> bf16 (x), 4 elems/thread ----------------
__global__ __launch_bounds__(256) void cvt_f32_bf16(
    const float* __restrict__ in, unsigned short* __restrict__ out, int n4)
{
    int i = blockIdx.x * 256 + threadIdx.x;
    if (i >= n4) return;
    float4 v = *(const float4*)&in[(size_t)i * 4];
    ushort4 o;
    o.x = f2bf(v.x); o.y = f2bf(v.y); o.z = f2bf(v.z); o.w = f2bf(v.w);
    *(ushort4*)&out[(size_t)i * 4] = o;
}

// ---------------- transpose+convert: in fp32 [R][C] -> out bf16 [C][R] ----------------
__global__ __launch_bounds__(256) void transpose_f32_bf16(
    const float* __restrict__ in, unsigned short* __restrict__ out,
    int R, int C)
{
    __shared__ unsigned short tile[32][33];
    int bx = blockIdx.x;
    int by = blockIdx.y;
    int x = bx*32 + threadIdx.x;
    int y0 = by*32 + threadIdx.y;
    #pragma unroll
    for (int i = 0; i < 32; i += 8)
        tile[threadIdx.y + i][threadIdx.x] = f2bf(in[(size_t)(y0 + i)*C + x]);
    __syncthreads();
    int xo = by*32 + threadIdx.x;
    int yo = bx*32 + threadIdx.y;
    #pragma unroll
    for (int i = 0; i < 32; i += 8)
        out[(size_t)(yo + i)*R + xo] = tile[threadIdx.x][threadIdx.y + i];
}

// ---------------- QKV GEMM: faithful m201 8-phase 256x256 port ----------------
// Round-7 post-mortem: my 4-phase port regressed (8 MFMA/phase, per-wave 64x64
// -> barrier cost without MFMA density; matches m232's null quadrant). This is
// the m201 geometry EXACTLY: 512 thr, 8 waves 2m x 4n, per-wave C = 128x64,
// acc[8][4], 16 MFMA per phase, BK=64, 2 K-tiles per iteration (8 phases).
//  - LDS 128 KB: 2 dbuf x 2 half x (A 128x64 | B 128x64) bf16. Stage
//    granularity = one matrix-half = 2 x global_load_lds(16B) per thread.
//  - Stage schedule (iter i, tiles 2i->dbuf0, 2i+1->dbuf1):
//      P1..P3: dbuf1 halves A1,B0,B1 of tile 2i+1 (its A0 staged prev P8)
//      P4..P7: dbuf0 halves A0,A1,B0,B1 of tile 2i+2
//      P8:     dbuf1 half  A0 of tile 2i+3
//    WAR-safe: wave w reads only A-half wm / B-half wn>>1; all reads of a
//    buffer complete (lgkm before in-phase MFMA) before the barrier that
//    precedes its first overwrite.
//  - Counted vmcnt at EXACTLY two points (T4): end-P4 vmcnt(2) guards dbuf1
//    before P5 reads; end-P8 vmcnt(2) guards dbuf0 before next P1 reads
//    (2 = the one younger half-stage in flight). vmcnt(0) only at the tail.
//  - T2 swizzle chunk^=row&7 both sides; T5 setprio around each MFMA cluster.
// Grid 384 = 32 x 12 (NXT=12); XCD-chunked swizzle (384%8==0).
// MODE 2 epilogue: n0<2048 -> bf16 QK[M][2048]; n0>=2048 -> V^T via LDS.
#define GTSTR 264
template <int MODE>
__global__ __launch_bounds__(512, 2) void gemm8p(
    const unsigned short* __restrict__ A, const unsigned short* __restrict__ BT,
    const float* __restrict__ bias, void* __restrict__ Cout, void* __restrict__ Cout2,
    int K, int N, int NXT)
{
    constexpr int SHSZ = (MODE == 2) ? 256*GTSTR : 65536;   // >= 65536 shorts
    __shared__ __align__(16) unsigned short Sh[SHSZ];

    const int tid  = threadIdx.x;
    const int lane = tid & 63;
    const int wave = tid >> 6;               // 0..7
    const int wm = wave >> 2, wn = wave & 3; // 2m x 4n
    const int quad = lane >> 4, l16 = lane & 15;

    const int nwg = gridDim.x, cpx = nwg >> 3;
    const int wg = (blockIdx.x & 7)*cpx + (blockIdx.x >> 3);
    const int by = wg / NXT, bx = wg - by*NXT;
    const int m0 = by*256, n0 = bx*256;

    f32x4 acc[8][4] = {};
    const int nk = K >> 6;                   // 16

    // (dbuf d, half h): A at (d*2+h)*16384, B at +8192 (shorts)
    auto SA = [&](int d, int h) -> unsigned short* { return &Sh[(d*2 + h)*16384]; };
    auto SB = [&](int d, int h) -> unsigned short* { return &Sh[(d*2 + h)*16384 + 8192]; };

    auto STG_A = [&](int d, int h, int t) {
        const int k0 = t << 6;
        unsigned short* dst = SA(d, h);
        #pragma unroll
        for (int p = 0; p < 2; ++p) {
            int c = p*512 + tid;
            int rl = c >> 3, ch = (c & 7) ^ (rl & 7);
            GLOAD_LDS16(&A[(size_t)(m0 + h*128 + rl)*K + k0 + ch*8], &dst[c*8]);
        }
    };
    auto STG_B = [&](int d, int h, int t) {
        const int k0 = t << 6;
        unsigned short* dst = SB(d, h);
        #pragma unroll
        for (int p = 0; p < 2; ++p) {
            int c = p*512 + tid;
            int rl = c >> 3, ch = (c & 7) ^ (rl & 7);
            GLOAD_LDS16(&BT[(size_t)(n0 + h*128 + rl)*K + k0 + ch*8], &dst[c*8]);
        }
    };
    auto RA = [&](int d, int mf, int kk) -> short8 {
        int rl = mf*16 + l16;                              // within half wm
        return *(const short8*)&SA(d, wm)[rl*64 + (((kk*4 + quad) ^ (rl & 7))*8)];
    };
    auto RB = [&](int d, int nf, int kk) -> short8 {
        int rl = (wn & 1)*64 + nf*16 + l16;                // within half wn>>1
        return *(const short8*)&SB(d, wn >> 1)[rl*64 + (((kk*4 + quad) ^ (rl & 7))*8)];
    };

    // prologue: tile0 all 4 halves -> dbuf0; tile1 A0 -> dbuf1
    STG_A(0, 0, 0); STG_A(0, 1, 0); STG_B(0, 0, 0); STG_B(0, 1, 0);
    STG_A(1, 0, 1);
    asm volatile("s_waitcnt vmcnt(2)" ::: "memory");       // dbuf0 landed
    __builtin_amdgcn_s_barrier();
    __builtin_amdgcn_sched_barrier(0);

    for (int i = 0; i < nk/2; ++i) {
        const int tb = 2*i + 1, tn0 = 2*i + 2, tn1 = 2*i + 3;
        const bool p2 = (tn0 < nk), p3 = (tn1 < nk);
        short8 a0[4][2], a1[4][2], b0[2][2], b1[2][2];

        // ================= K-tile 2i (dbuf 0) =================
        // ---- P1: quadrant (m-lo, n-lo); reads A[0-3], B[0-1]
        #pragma unroll
        for (int mf = 0; mf < 4; ++mf) { a0[mf][0] = RA(0, mf, 0); a0[mf][1] = RA(0, mf, 1); }
        #pragma unroll
        for (int nf = 0; nf < 2; ++nf) { b0[nf][0] = RB(0, nf, 0); b0[nf][1] = RB(0, nf, 1); }
        STG_A(1, 1, tb);
        __builtin_amdgcn_s_barrier();
        __builtin_amdgcn_s_setprio(1);
        #pragma unroll
        for (int mf = 0; mf < 4; ++mf)
            #pragma unroll
            for (int nf = 0; nf < 2; ++nf)
                #pragma unroll
                for (int kk = 0; kk < 2; ++kk)
                    acc[mf][nf] = __builtin_amdgcn_mfma_f32_16x16x32_bf16(
                        a0[mf][kk], b0[nf][kk], acc[mf][nf], 0, 0, 0);
        __builtin_amdgcn_s_setprio(0);
        __builtin_amdgcn_s_barrier();

        // ---- P2: (m-lo, n-hi); reads B[2-3]
        #pragma unroll
        for (int nf = 0; nf < 2; ++nf) { b1[nf][0] = RB(0, 2+nf, 0); b1[nf][1] = RB(0, 2+nf, 1); }
        STG_B(1, 0, tb);
        __builtin_amdgcn_s_barrier();
        __builtin_amdgcn_s_setprio(1);
        #pragma unroll
        for (int mf = 0; mf < 4; ++mf)
            #pragma unroll
            for (int nf = 0; nf < 2; ++nf)
                #pragma unroll
                for (int kk = 0; kk < 2; ++kk)
                    acc[mf][2+nf] = __builtin_amdgcn_mfma_f32_16x16x32_bf16(
                        a0[mf][kk], b1[nf][kk], acc[mf][2+nf], 0, 0, 0);
        __builtin_amdgcn_s_setprio(0);
        __builtin_amdgcn_s_barrier();

        // ---- P3: (m-hi, n-lo); reads A[4-7]
        #pragma unroll
        for (int mf = 0; mf < 4; ++mf) { a1[mf][0] = RA(0, 4+mf, 0); a1[mf][1] = RA(0, 4+mf, 1); }
        STG_B(1, 1, tb);
        __builtin_amdgcn_s_barrier();
        __builtin_amdgcn_s_setprio(1);
        #pragma unroll
        for (int mf = 0; mf < 4; ++mf)
            #pragma unroll
            for (int nf = 0; nf < 2; ++nf)
                #pragma unroll
                for (int kk = 0; kk < 2; ++kk)
                    acc[4+mf][nf] = __builtin_amdgcn_mfma_f32_16x16x32_bf16(
                        a1[mf][kk], b0[nf][kk], acc[4+mf][nf], 0, 0, 0);
        __builtin_amdgcn_s_setprio(0);
        __builtin_amdgcn_s_barrier();

        // ---- P4: (m-hi, n-hi); no reads. End: counted vmcnt guards dbuf1.
        if (p2) STG_A(0, 0, tn0);
        __builtin_amdgcn_s_barrier();
        __builtin_amdgcn_s_setprio(1);
        #pragma unroll
        for (int mf = 0; mf < 4; ++mf)
            #pragma unroll
            for (int nf = 0; nf < 2; ++nf)
                #pragma unroll
                for (int kk = 0; kk < 2; ++kk)
                    acc[4+mf][2+nf] = __builtin_amdgcn_mfma_f32_16x16x32_bf16(
                        a1[mf][kk], b1[nf][kk], acc[4+mf][2+nf], 0, 0, 0);
        __builtin_amdgcn_s_setprio(0);
        if (p2) asm volatile("s_waitcnt vmcnt(2)" ::: "memory");
        else    asm volatile("s_waitcnt vmcnt(0)" ::: "memory");
        __builtin_amdgcn_s_barrier();
        __builtin_amdgcn_sched_barrier(0);

        // ================= K-tile 2i+1 (dbuf 1) =================
        // ---- P5
        #pragma unroll
        for (int mf = 0; mf < 4; ++mf) { a0[mf][0] = RA(1, mf, 0); a0[mf][1] = RA(1, mf, 1); }
        #pragma unroll
        for (int nf = 0; nf < 2; ++nf) { b0[nf][0] = RB(1, nf, 0); b0[nf][1] = RB(1, nf, 1); }
        if (p2) STG_A(0, 1, tn0);
        __builtin_amdgcn_s_barrier();
        __builtin_amdgcn_s_setprio(1);
        #pragma unroll
        for (int mf = 0; mf < 4; ++mf)
            #pragma unroll
            for (int nf = 0; nf < 2; ++nf)
                #pragma unroll
                for (int kk = 0; kk < 2; ++kk)
                    acc[mf][nf] = __builtin_amdgcn_mfma_f32_16x16x32_bf16(
                        a0[mf][kk], b0[nf][kk], acc[mf][nf], 0, 0, 0);
        __builtin_amdgcn_s_setprio(0);
        __builtin_amdgcn_s_barrier();

        // ---- P6
        #pragma unroll
        for (int nf = 0; nf < 2; ++nf) { b1[nf][0] = RB(1, 2+nf, 0); b1[nf][1] = RB(1, 2+nf, 1); }
        if (p2) STG_B(0, 0, tn0);
        __builtin_amdgcn_s_barrier();
        __builtin_amdgcn_s_setprio(1);
        #pragma unroll
        for (int mf = 0; mf < 4; ++mf)
            #pragma unroll
            for (int nf = 0; nf < 2; ++nf)
                #pragma unroll
                for (int kk = 0; kk < 2; ++kk)
                    acc[mf][2+nf] = __builtin_amdgcn_mfma_f32_16x16x32_bf16(
                        a0[mf][kk], b1[nf][kk], acc[mf][2+nf], 0, 0, 0);
        __builtin_amdgcn_s_setprio(0);
        __builtin_amdgcn_s_barrier();

        // ---- P7
        #pragma unroll
        for (int mf = 0; mf < 4; ++mf) { a1[mf][0] = RA(1, 4+mf, 0); a1[mf][1] = RA(1, 4+mf, 1); }
        if (p2) STG_B(0, 1, tn0);
        __builtin_amdgcn_s_barrier();
        __builtin_amdgcn_s_setprio(1);
        #pragma unroll
        for (int mf = 0; mf < 4; ++mf)
            #pragma unroll
            for (int nf = 0; nf < 2; ++nf)
                #pragma unroll
                for (int kk = 0; kk < 2; ++kk)
                    acc[4+mf][nf] = __builtin_amdgcn_mfma_f32_16x16x32_bf16(
                        a1[mf][kk], b0[nf][kk], acc[4+mf][nf], 0, 0, 0);
        __builtin_amdgcn_s_setprio(0);
        __builtin_amdgcn_s_barrier();

        // ---- P8: end: counted vmcnt guards dbuf0 for next iteration's P1.
        if (p3) STG_A(1, 0, tn1);
        __builtin_amdgcn_s_barrier();
        __builtin_amdgcn_s_setprio(1);
        #pragma unroll
        for (int mf = 0; mf < 4; ++mf)
            #pragma unroll
            for (int nf = 0; nf < 2; ++nf)
                #pragma unroll
                for (int kk = 0; kk < 2; ++kk)
                    acc[4+mf][2+nf] = __builtin_amdgcn_mfma_f32_16x16x32_bf16(
                        a1[mf][kk], b1[nf][kk], acc[4+mf][2+nf], 0, 0, 0);
        __builtin_amdgcn_s_setprio(0);
        if (p3) asm volatile("s_waitcnt vmcnt(2)" ::: "memory");
        else    asm volatile("s_waitcnt vmcnt(0)" ::: "memory");
        __builtin_amdgcn_s_barrier();
        __builtin_amdgcn_sched_barrier(0);
    }

    if (MODE == 2 && n0 >= 2048) {
        // V third: transpose via LDS (vm drained by tail vmcnt(0); reads done)
        #pragma unroll
        for (int ni = 0; ni < 4; ++ni) {
            int nl = wn*64 + ni*16 + l16;            // local n 0..255
            float bv = bias[n0 + nl];
            #pragma unroll
            for (int mi = 0; mi < 8; ++mi) {
                ushort4 pk;
                pk.x = f2bf(acc[mi][ni][0] + bv);
                pk.y = f2bf(acc[mi][ni][1] + bv);
                pk.z = f2bf(acc[mi][ni][2] + bv);
                pk.w = f2bf(acc[mi][ni][3] + bv);
                *(ushort4*)&Sh[nl*GTSTR + wm*128 + mi*16 + quad*4] = pk;
            }
        }
        __builtin_amdgcn_s_barrier();
        const int bb = m0 >> 11, t0 = m0 & 2047;
        #pragma unroll
        for (int p = 0; p < 16; ++p) {
            int c = p*512 + tid;
            int row = c >> 5, ch = c & 31;           // row: local n, ch: 8-short m-chunk
            int nv = n0 + row - 2048;
            int hv = nv >> 6, dv = nv & 63;
            *(uint4*)&((unsigned short*)Cout2)[((size_t)((bb*16 + hv)*64 + dv))*2048 + t0 + ch*8] =
                *(uint4*)&Sh[row*GTSTR + ch*8];
        }
        return;
    }

    const int cstride = (MODE == 2) ? 2048 : N;
    #pragma unroll
    for (int ni = 0; ni < 4; ++ni) {
        int n = n0 + wn*64 + ni*16 + l16;
        float bv = bias[n];
        #pragma unroll
        for (int mi = 0; mi < 8; ++mi) {
            #pragma unroll
            for (int r = 0; r < 4; ++r) {
                int m = m0 + wm*128 + mi*16 + quad*4 + r;
                float val = acc[mi][ni][r] + bv;
                if (MODE == 1)
                    ((float*)Cout)[(size_t)m*cstride + n] = val;
                else
                    ((unsigned short*)Cout)[(size_t)m*cstride + n] = f2bf(val);
            }
        }
    }
}

// ---------------- big-tile MFMA bf16 GEMM (round-6 structure, out-proj) --------
// 2 phases/tile, whole-tile dbuf, counted vmcnt(6) (0 at last tile), T2 swizzle,
// exact-fit grid 256 = 1 block/CU for BM=128 x BN=256. Best measured for
// out-proj; kept verbatim from round 6.
template <int MODE, int BM, int BN>
__global__ __launch_bounds__(512, 2) void gemm_big(
    const unsigned short* __restrict__ A, const unsigned short* __restrict__ BT,
    const float* __restrict__ bias, void* __restrict__ Cout, void* __restrict__ Cout2,
    int K, int N, int NXT)
{
    constexpr int SHSZ = 2*(BM+BN)*64;               // shorts; 96 KB
    __shared__ __align__(16) unsigned short Sh[SHSZ];

    const int tid  = threadIdx.x;
    const int lane = tid & 63;
    const int wave = tid >> 6;                       // 0..7
    constexpr int WNG = BN/64;                       // waves along n
    const int wm = wave / WNG, wn = wave % WNG;
    const int quad = lane >> 4, l16 = lane & 15;

    const int nwg = gridDim.x, cpx = nwg >> 3;
    const int wg = (blockIdx.x & 7)*cpx + (blockIdx.x >> 3);
    const int by = wg / NXT, bx = wg - by*NXT;
    const int m0 = by*BM, n0 = bx*BN;

    f32x4 acc[4][4] = {};
    const int nk = K >> 6;

    auto STAGE = [&](int t, int buf) {
        const int k0 = t << 6;
        unsigned short* Ab = &Sh[buf*(BM*64)];
        unsigned short* Bb = &Sh[2*BM*64 + buf*(BN*64)];
        #pragma unroll
        for (int p = 0; p < BM/64; ++p) {
            int c = p*512 + tid;
            int row = c >> 3, ch = (c & 7) ^ (row & 7);
            GLOAD_LDS16(&A[(size_t)(m0 + row)*K + k0 + ch*8], &Ab[c*8]);
        }
        #pragma unroll
        for (int p = 0; p < BN/64; ++p) {
            int c = p*512 + tid;
            int row = c >> 3, ch = (c & 7) ^ (row & 7);
            GLOAD_LDS16(&BT[(size_t)(n0 + row)*K + k0 + ch*8], &Bb[c*8]);
        }
    };

    STAGE(0, 0);
    STAGE(1, 1);

    for (int t = 0; t < nk; ++t) {
        const int buf = t & 1;
        const unsigned short* Ab = &Sh[buf*(BM*64)];
        const unsigned short* Bb = &Sh[2*BM*64 + buf*(BN*64)];

        if (t == nk - 1) asm volatile("s_waitcnt vmcnt(0)" ::: "memory");
        else             asm volatile("s_waitcnt vmcnt(6)" ::: "memory");
        __builtin_amdgcn_s_barrier();
        __builtin_amdgcn_sched_barrier(0);           // no ds_read hoists above

        short8 fa[4][2], fb[2][2];

        // ---- phase 0: all m x n-lo
        #pragma unroll
        for (int mi = 0; mi < 4; ++mi)
            #pragma unroll
            for (int kk = 0; kk < 2; ++kk) {
                int row = wm*64 + mi*16 + l16;
                fa[mi][kk] = *(const short8*)&Ab[row*64 + (((kk*4 + quad) ^ (row & 7))*8)];
            }
        #pragma unroll
        for (int ni = 0; ni < 2; ++ni)
            #pragma unroll
            for (int kk = 0; kk < 2; ++kk) {
                int row = wn*64 + ni*16 + l16;
                fb[ni][kk] = *(const short8*)&Bb[row*64 + (((kk*4 + quad) ^ (row & 7))*8)];
            }
        __builtin_amdgcn_s_barrier();
        __builtin_amdgcn_s_setprio(1);
        #pragma unroll
        for (int mi = 0; mi < 4; ++mi)
            #pragma unroll
            for (int ni = 0; ni < 2; ++ni)
                #pragma unroll
                for (int kk = 0; kk < 2; ++kk)
                    acc[mi][ni] = __builtin_amdgcn_mfma_f32_16x16x32_bf16(
                        fa[mi][kk], fb[ni][kk], acc[mi][ni], 0, 0, 0);
        __builtin_amdgcn_s_setprio(0);
        __builtin_amdgcn_s_barrier();

        // ---- phase 1: all m x n-hi
        #pragma unroll
        for (int ni = 0; ni < 2; ++ni)
            #pragma unroll
            for (int kk = 0; kk < 2; ++kk) {
                int row = wn*64 + 32 + ni*16 + l16;
                fb[ni][kk] = *(const short8*)&Bb[row*64 + (((kk*4 + quad) ^ (row & 7))*8)];
            }
        __builtin_amdgcn_s_barrier();
        __builtin_amdgcn_s_setprio(1);
        #pragma unroll
        for (int mi = 0; mi < 4; ++mi)
            #pragma unroll
            for (int ni = 0; ni < 2; ++ni)
                #pragma unroll
                for (int kk = 0; kk < 2; ++kk)
                    acc[mi][2 + ni] = __builtin_amdgcn_mfma_f32_16x16x32_bf16(
                        fa[mi][kk], fb[ni][kk], acc[mi][2 + ni], 0, 0, 0);
        __builtin_amdgcn_s_setprio(0);
        __builtin_amdgcn_s_barrier();                // all buf-t reads consumed

        __builtin_amdgcn_sched_barrier(0);           // STAGE must not hoist above
        if (t + 2 < nk) STAGE(t + 2, buf);           // prefetch 2 tiles ahead
    }

    const int cstride = (MODE == 2) ? 2048 : N;
    #pragma unroll
    for (int ni = 0; ni < 4; ++ni) {
        int n = n0 + wn*64 + ni*16 + l16;
        float bv = bias[n];
        #pragma unroll
        for (int mi = 0; mi < 4; ++mi) {
            #pragma unroll
            for (int r = 0; r < 4; ++r) {
                int m = m0 + wm*64 + mi*16 + quad*4 + r;
                float val = acc[mi][ni][r] + bv;
                if (MODE == 1)
                    ((float*)Cout)[(size_t)m*cstride + n] = val;
                else
                    ((unsigned short*)Cout)[(size_t)m*cstride + n] = f2bf(val);
            }
        }
    }
}

// ---------------- MFMA flash attention: 4-wave block, LDS K+V, paired q-chunks ----
// (unchanged: best measured 122-123us. Uniform 34 k-tiles/block via
// complementary q-chunk pair (a, 15-a); K/V LDS dbuf, 2-phase pipeline, DPP
// softmax; XCD pinning i&7.)
#define PST 72
__global__ __launch_bounds__(256, 3) void attn_mfma(
    const unsigned short* __restrict__ QK, const unsigned short* __restrict__ VT,
    unsigned short* __restrict__ Y)
{
    // LDS: K dbuf 2x4096 shorts, V dbuf 2x4096 shorts, P 4 waves x 32 x PST
    __shared__ __align__(16) unsigned short Sh[16384 + 4*32*PST];

    const int tid  = threadIdx.x;
    const int lane = tid & 63;
    const int wave = tid >> 6;
    const int quad = lane >> 4, l16 = lane & 15;

    const int i = blockIdx.x;            // 0..511
    const int xcd = i & 7, j = i >> 3;   // j 0..63
    const int a = j & 7;                 // chunk-pair index: handles qc=a then 15-a
    const int u = j >> 3;                // bh-group 0..7
    const int bh2 = xcd + 8*u;
    const int b = bh2 >> 4, h = bh2 & 15;
    const size_t qkbase = (size_t)(b*TT) * 2048;
    const size_t vbase  = (size_t)(bh2*64) * 2048;
    const int qcol = h*64, kcol = 1024 + h*64;
    const float C2 = 0.18033688011112042f;   // (1/sqrt(64)) * log2(e)

    unsigned short* Pw = &Sh[16384 + wave*(32*PST)];

    const int nk1 = 2*a + 2;             // pass-0 tile count (qc = a)
    const int ntot = 34;                 // uniform for all blocks

    short8 aq[2][2];
    f32x4 o[2][4];
    float mold[2][4], lsum[2][4];
    int q0w = a*128 + wave*32;           // current pass q-row base for this wave

    auto LOADQ = [&]() {
        #pragma unroll
        for (int mt = 0; mt < 2; ++mt)
            #pragma unroll
            for (int kk = 0; kk < 2; ++kk)
                aq[mt][kk] = *(const short8*)&QK[qkbase + (size_t)(q0w + mt*16 + l16)*2048
                                                + qcol + kk*32 + quad*8];
        #pragma unroll
        for (int mt = 0; mt < 2; ++mt)
            #pragma unroll
            for (int r = 0; r < 4; ++r) { mold[mt][r] = -3.0e38f; lsum[mt][r] = 0.0f; }
        #pragma unroll
        for (int mt = 0; mt < 2; ++mt)
            #pragma unroll
            for (int dt = 0; dt < 4; ++dt) { f32x4 z = {}; o[mt][dt] = z; }
    };
    auto FINALIZE = [&]() {
        #pragma unroll
        for (int mt = 0; mt < 2; ++mt)
            #pragma unroll
            for (int r = 0; r < 4; ++r) {
                float inv = 1.0f / lsum[mt][r];
                int tq = q0w + mt*16 + quad*4 + r;
                #pragma unroll
                for (int dt = 0; dt < 4; ++dt)
                    Y[((size_t)(b*TT + tq))*DD + h*64 + dt*16 + l16] = f2bf(o[mt][dt][r] * inv);
            }
    };

    auto STAGE = [&](int buf, int k0) {
        unsigned short* Kb = &Sh[buf*4096];
        unsigned short* Vb = &Sh[8192 + buf*4096];
        #pragma unroll
        for (int p = 0; p < 2; ++p) {
            int c = p*256 + tid;               // 16B chunk index, linear in lane
            int r = c >> 3;
            int ch = (c & 7) ^ (r & 7);        // source chunk (inverse swizzle)
            GLOAD_LDS16(&QK[qkbase + (size_t)(k0 + r)*2048 + kcol + ch*8], &Kb[c*8]);
        }
        #pragma unroll
        for (int p = 0; p < 2; ++p) {
            int c = p*256 + tid;
            int r = c >> 3;                    // r = head-dim row of VT
            int ch = (c & 7) ^ (r & 7);
            GLOAD_LDS16(&VT[vbase + (size_t)r*2048 + k0 + ch*8], &Vb[c*8]);
        }
    };

    LOADQ();
    STAGE(0, 0);
    asm volatile("s_waitcnt vmcnt(0)" ::: "memory");
    __builtin_amdgcn_s_barrier();

    int cur = 0;
    for (int t = 0; t < ntot; ++t) {
        const int k0 = ((t < nk1) ? t : t - nk1) * 64;
        if (t + 1 < ntot) {
            const int t1 = t + 1;
            STAGE(cur ^ 1, ((t1 < nk1) ? t1 : t1 - nk1) * 64);   // async prefetch
        }
        if (t == nk1) {
            FINALIZE();
            q0w = (15 - a)*128 + wave*32;
            LOADQ();
        }

        if (k0 <= q0w + 31) {                  // wave-uniform causal activity guard
            const unsigned short* Kb = &Sh[cur*4096];
            const unsigned short* Vb = &Sh[8192 + cur*4096];

            // ---- S = Q K^T from LDS (swizzled reads)
            f32x4 s[2][4];
            #pragma unroll
            for (int nt = 0; nt < 4; ++nt) {
                if (k0 + nt*16 <= q0w + 31) {
                    f32x4 z = {};
                    s[0][nt] = z; s[1][nt] = z;
                    #pragma unroll
                    for (int kk = 0; kk < 2; ++kk) {
                        int r = nt*16 + l16;
                        short8 bk = *(const short8*)&Kb[r*64 + (((kk*4 + quad) ^ (r & 7))*8)];
                        s[0][nt] = __builtin_amdgcn_mfma_f32_16x16x32_bf16(aq[0][kk], bk, s[0][nt], 0, 0, 0);
                        s[1][nt] = __builtin_amdgcn_mfma_f32_16x16x32_bf16(aq[1][kk], bk, s[1][nt], 0, 0, 0);
                    }
                } else {
                    #pragma unroll
                    for (int r = 0; r < 4; ++r) { s[0][nt][r] = -3.0e38f; s[1][nt][r] = -3.0e38f; }
                }
            }

            // ---- issue V-frag LDS loads now; latency hides under softmax
            short8 bv[2][4];
            #pragma unroll
            for (int kk = 0; kk < 2; ++kk)
                #pragma unroll
                for (int dt = 0; dt < 4; ++dt) {
                    int r = dt*16 + l16;
                    bv[kk][dt] = *(const short8*)&Vb[r*64 + (((kk*4 + quad) ^ (r & 7))*8)];
                }

            // ---- element causal mask (straddling tiles only)
            if (k0 + 63 > q0w) {
                #pragma unroll
                for (int mt = 0; mt < 2; ++mt)
                    #pragma unroll
                    for (int nt = 0; nt < 4; ++nt)
                        #pragma unroll
                        for (int r = 0; r < 4; ++r) {
                            int kg = k0 + nt*16 + l16;
                            int qg = q0w + mt*16 + quad*4 + r;
                            if (kg > qg) s[mt][nt][r] = -3.0e38f;
                        }
            }

            // ---- online softmax (exp2 domain), DPP reductions
            float m2n[2][4], al[2][4];
            #pragma unroll
            for (int mt = 0; mt < 2; ++mt)
                #pragma unroll
                for (int r = 0; r < 4; ++r) {
                    float rm = fmaxf(fmaxf(s[mt][0][r], s[mt][1][r]),
                                     fmaxf(s[mt][2][r], s[mt][3][r]));
                    rm = red_max16(rm);
                    float m2 = fmaxf(mold[mt][r], rm * C2);
                    al[mt][r]  = EXP2(mold[mt][r] - m2);
                    m2n[mt][r] = m2;
                }
            float rs[2][4] = {};
            #pragma unroll
            for (int mt = 0; mt < 2; ++mt)
                #pragma unroll
                for (int nt = 0; nt < 4; ++nt)
                    #pragma unroll
                    for (int r = 0; r < 4; ++r) {
                        float p = EXP2(fmaf(s[mt][nt][r], C2, -m2n[mt][r]));
                        s[mt][nt][r] = p;
                        rs[mt][r] += p;
                    }
            #pragma unroll
            for (int mt = 0; mt < 2; ++mt)
                #pragma unroll
                for (int r = 0; r < 4; ++r) {
                    float tsum = red_sum16(rs[mt][r]);
                    lsum[mt][r] = lsum[mt][r]*al[mt][r] + tsum;
                    mold[mt][r] = m2n[mt][r];
                }

            // ---- P -> LDS (wave-private buffer; same-wave RAW, no barrier)
            #pragma unroll
            for (int mt = 0; mt < 2; ++mt)
                #pragma unroll
                for (int nt = 0; nt < 4; ++nt)
                    #pragma unroll
                    for (int r = 0; r < 4; ++r) {
                        union { float f; uint32_t u; } c; c.f = s[mt][nt][r];
                        Pw[(mt*16 + quad*4 + r)*PST + nt*16 + l16] =
                            (unsigned short)((c.u + 0x8000u) >> 16);
                    }

            // ---- O = O*alpha + P V
            #pragma unroll
            for (int mt = 0; mt < 2; ++mt)
                #pragma unroll
                for (int dt = 0; dt < 4; ++dt)
                    #pragma unroll
                    for (int r = 0; r < 4; ++r)
                        o[mt][dt][r] *= al[mt][r];
            #pragma unroll
            for (int kk = 0; kk < 2; ++kk) {
                short8 ap0 = *(short8*)&Pw[(     l16)*PST + kk*32 + quad*8];
                short8 ap1 = *(short8*)&Pw[(16 + l16)*PST + kk*32 + quad*8];
                #pragma unroll
                for (int dt = 0; dt < 4; ++dt) {
                    o[0][dt] = __builtin_amdgcn_mfma_f32_16x16x32_bf16(ap0, bv[kk][dt], o[0][dt], 0, 0, 0);
                    o[1][dt] = __builtin_amdgcn_mfma_f32_16x16x32_bf16(ap1, bv[kk][dt], o[1][dt], 0, 0, 0);
                }
            }
        }

        asm volatile("s_waitcnt vmcnt(0)" ::: "memory");  // next-tile stage landed
        __builtin_amdgcn_s_barrier();                     // all waves' stage + reads done
        cur ^= 1;
    }

    FINALIZE();   // pass-1 (chunk 15-a) output
}

extern "C" void kernel_launch(void* const* d_in, const int* in_sizes, int n_in,
                              void* d_out, int out_size, void* d_ws, size_t ws_size,
                              hipStream_t stream)
{
    const float* x    = (const float*)d_in[0];   // [4,2048,1024] fp32
    // d_in[1] = causal_mask (int32) — causality implemented analytically, unused
    const float* wqkv = (const float*)d_in[2];   // [1024][3072] fp32
    const float* bqkv = (const float*)d_in[3];   // [3072] fp32
    const float* wout = (const float*)d_in[4];   // [1024][1024] fp32
    const float* bout = (const float*)d_in[5];   // [1024] fp32
    float* out = (float*)d_out;                  // [4,2048,1024] fp32

    char* ws = (char*)d_ws;
    unsigned short* Xb    = (unsigned short*)ws;                    // 16 MB
    unsigned short* WqkvT = (unsigned short*)(ws + 16777216);       // 6 MB
    unsigned short* WoutT = (unsigned short*)(ws + 23068672);       // 2 MB
    unsigned short* QK    = (unsigned short*)(ws + 25165824);       // 32 MB [M][2048]
    unsigned short* VTb   = (unsigned short*)(ws + 58720256);       // 16 MB [(bh*64+d)][2048]
    unsigned short* Ybuf  = (unsigned short*)(ws + 75497472);       // 16 MB

    cvt_f32_bf16<<<(M1*KDIM/4 + 255)/256, 256, 0, stream>>>(x, Xb, M1*KDIM/4);
    transpose_f32_bf16<<<dim3(N1/32, KDIM/32), dim3(32, 8), 0, stream>>>(wqkv, WqkvT, KDIM, N1);
    transpose_f32_bf16<<<dim3(DD/32, KDIM/32), dim3(32, 8), 0, stream>>>(wout, WoutT, KDIM, DD);
    gemm8p<2><<<dim3(384), 512, 0, stream>>>(Xb, WqkvT, bqkv, QK, VTb, KDIM, N1, 12);
    attn_mfma<<<dim3(512), 256, 0, stream>>>(QK, VTb, Ybuf);
    gemm_big<1, 128, 256><<<dim3(256), 512, 0, stream>>>(Ybuf, WoutT, bout, out, nullptr, KDIM, DD, 4);
}

// Round 9
// 292.515 us; speedup vs baseline: 1.1069x; 1.0678x over previous
//
#include <hip/hip_runtime.h>
#include <hip/hip_bf16.h>
#include <stdint.h>

// Problem constants
#define BB 4
#define TT 2048
#define DD 1024
#define HH 16
#define HDD 64
// derived
#define M1 (BB*TT)      // 8192 rows
#define N1 (3*DD)       // 3072
#define KDIM DD         // 1024

typedef __attribute__((ext_vector_type(8))) short short8;   // 8 bf16 MFMA operand
typedef __attribute__((ext_vector_type(4))) float f32x4;

#if __has_builtin(__builtin_amdgcn_exp2f)
#define EXP2(x) __builtin_amdgcn_exp2f(x)
#else
#define EXP2(x) exp2f(x)
#endif

// async global->LDS, 16B per lane (global_load_lds_dwordx4)
#define GLOAD_LDS16(gp, lp) \
    __builtin_amdgcn_global_load_lds( \
        (const __attribute__((address_space(1))) void*)(gp), \
        (__attribute__((address_space(3))) void*)(lp), 16, 0, 0)

__device__ __forceinline__ float bf2f(unsigned short u) {
    union { uint32_t u32; float f; } c; c.u32 = ((uint32_t)u) << 16; return c.f;
}
__device__ __forceinline__ unsigned short f2bf(float f) {
    union { float f; uint32_t u32; } c; c.f = f;
    uint32_t u = c.u32;
    return (unsigned short)((u + 0x7FFFu + ((u >> 16) & 1u)) >> 16);  // RNE
}

// DPP row_ror rotate-reduce within the 16-lane DPP row.
template <int CTRL>
__device__ __forceinline__ float dpp_ror(float x) {
    union { float f; int i; } u, r;
    u.f = x;
    r.i = __builtin_amdgcn_update_dpp(u.i, u.i, CTRL, 0xF, 0xF, false);
    return r.f;
}
__device__ __forceinline__ float red_max16(float x) {
    x = fmaxf(x, dpp_ror<0x128>(x));   // row_ror:8
    x = fmaxf(x, dpp_ror<0x124>(x));   // row_ror:4
    x = fmaxf(x, dpp_ror<0x122>(x));   // row_ror:2
    x = fmaxf(x, dpp_ror<0x121>(x));   // row_ror:1
    return x;
}
__device__ __forceinline__ float red_sum16(float x) {
    x += dpp_ror<0x128>(x);
    x += dpp_ror<0x124>(x);
    x += dpp_ror<0x122>(x);
    x += dpp_ror<0x121>(x);
    return x;
}

// ---------------- elementwise fp32 -> bf16 (x), 4 elems/thread ----------------
__global__ __launch_bounds__(256) void cvt_f32_bf16(
    const float* __restrict__ in, unsigned short* __restrict__ out, int n4)
{
    int i = blockIdx.x * 256 + threadIdx.x;
    if (i >= n4) return;
    float4 v = *(const float4*)&in[(size_t)i * 4];
    ushort4 o;
    o.x = f2bf(v.x); o.y = f2bf(v.y); o.z = f2bf(v.z); o.w = f2bf(v.w);
    *(ushort4*)&out[(size_t)i * 4] = o;
}

// ---------------- transpose+convert: in fp32 [R][C] -> out bf16 [C][R] ----------------
__global__ __launch_bounds__(256) void transpose_f32_bf16(
    const float* __restrict__ in, unsigned short* __restrict__ out,
    int R, int C)
{
    __shared__ unsigned short tile[32][33];
    int bx = blockIdx.x;
    int by = blockIdx.y;
    int x = bx*32 + threadIdx.x;
    int y0 = by*32 + threadIdx.y;
    #pragma unroll
    for (int i = 0; i < 32; i += 8)
        tile[threadIdx.y + i][threadIdx.x] = f2bf(in[(size_t)(y0 + i)*C + x]);
    __syncthreads();
    int xo = by*32 + threadIdx.x;
    int yo = bx*32 + threadIdx.y;
    #pragma unroll
    for (int i = 0; i < 32; i += 8)
        out[(size_t)(yo + i)*R + xo] = tile[threadIdx.x][threadIdx.y + i];
}

// ---------------- QKV GEMM: m201 8-phase 256x256 (round-8, best measured) -------
#define GTSTR 264
template <int MODE>
__global__ __launch_bounds__(512, 2) void gemm8p(
    const unsigned short* __restrict__ A, const unsigned short* __restrict__ BT,
    const float* __restrict__ bias, void* __restrict__ Cout, void* __restrict__ Cout2,
    int K, int N, int NXT)
{
    constexpr int SHSZ = (MODE == 2) ? 256*GTSTR : 65536;   // >= 65536 shorts
    __shared__ __align__(16) unsigned short Sh[SHSZ];

    const int tid  = threadIdx.x;
    const int lane = tid & 63;
    const int wave = tid >> 6;               // 0..7
    const int wm = wave >> 2, wn = wave & 3; // 2m x 4n
    const int quad = lane >> 4, l16 = lane & 15;

    const int nwg = gridDim.x, cpx = nwg >> 3;
    const int wg = (blockIdx.x & 7)*cpx + (blockIdx.x >> 3);
    const int by = wg / NXT, bx = wg - by*NXT;
    const int m0 = by*256, n0 = bx*256;

    f32x4 acc[8][4] = {};
    const int nk = K >> 6;                   // 16

    auto SA = [&](int d, int h) -> unsigned short* { return &Sh[(d*2 + h)*16384]; };
    auto SB = [&](int d, int h) -> unsigned short* { return &Sh[(d*2 + h)*16384 + 8192]; };

    auto STG_A = [&](int d, int h, int t) {
        const int k0 = t << 6;
        unsigned short* dst = SA(d, h);
        #pragma unroll
        for (int p = 0; p < 2; ++p) {
            int c = p*512 + tid;
            int rl = c >> 3, ch = (c & 7) ^ (rl & 7);
            GLOAD_LDS16(&A[(size_t)(m0 + h*128 + rl)*K + k0 + ch*8], &dst[c*8]);
        }
    };
    auto STG_B = [&](int d, int h, int t) {
        const int k0 = t << 6;
        unsigned short* dst = SB(d, h);
        #pragma unroll
        for (int p = 0; p < 2; ++p) {
            int c = p*512 + tid;
            int rl = c >> 3, ch = (c & 7) ^ (rl & 7);
            GLOAD_LDS16(&BT[(size_t)(n0 + h*128 + rl)*K + k0 + ch*8], &dst[c*8]);
        }
    };
    auto RA = [&](int d, int mf, int kk) -> short8 {
        int rl = mf*16 + l16;                              // within half wm
        return *(const short8*)&SA(d, wm)[rl*64 + (((kk*4 + quad) ^ (rl & 7))*8)];
    };
    auto RB = [&](int d, int nf, int kk) -> short8 {
        int rl = (wn & 1)*64 + nf*16 + l16;                // within half wn>>1
        return *(const short8*)&SB(d, wn >> 1)[rl*64 + (((kk*4 + quad) ^ (rl & 7))*8)];
    };

    // prologue: tile0 all 4 halves -> dbuf0; tile1 A0 -> dbuf1
    STG_A(0, 0, 0); STG_A(0, 1, 0); STG_B(0, 0, 0); STG_B(0, 1, 0);
    STG_A(1, 0, 1);
    asm volatile("s_waitcnt vmcnt(2)" ::: "memory");       // dbuf0 landed
    __builtin_amdgcn_s_barrier();
    __builtin_amdgcn_sched_barrier(0);

    for (int i = 0; i < nk/2; ++i) {
        const int tb = 2*i + 1, tn0 = 2*i + 2, tn1 = 2*i + 3;
        const bool p2 = (tn0 < nk), p3 = (tn1 < nk);
        short8 a0[4][2], a1[4][2], b0[2][2], b1[2][2];

        // ================= K-tile 2i (dbuf 0) =================
        // ---- P1: (m-lo, n-lo)
        #pragma unroll
        for (int mf = 0; mf < 4; ++mf) { a0[mf][0] = RA(0, mf, 0); a0[mf][1] = RA(0, mf, 1); }
        #pragma unroll
        for (int nf = 0; nf < 2; ++nf) { b0[nf][0] = RB(0, nf, 0); b0[nf][1] = RB(0, nf, 1); }
        STG_A(1, 1, tb);
        __builtin_amdgcn_s_barrier();
        __builtin_amdgcn_s_setprio(1);
        #pragma unroll
        for (int mf = 0; mf < 4; ++mf)
            #pragma unroll
            for (int nf = 0; nf < 2; ++nf)
                #pragma unroll
                for (int kk = 0; kk < 2; ++kk)
                    acc[mf][nf] = __builtin_amdgcn_mfma_f32_16x16x32_bf16(
                        a0[mf][kk], b0[nf][kk], acc[mf][nf], 0, 0, 0);
        __builtin_amdgcn_s_setprio(0);
        __builtin_amdgcn_s_barrier();

        // ---- P2: (m-lo, n-hi)
        #pragma unroll
        for (int nf = 0; nf < 2; ++nf) { b1[nf][0] = RB(0, 2+nf, 0); b1[nf][1] = RB(0, 2+nf, 1); }
        STG_B(1, 0, tb);
        __builtin_amdgcn_s_barrier();
        __builtin_amdgcn_s_setprio(1);
        #pragma unroll
        for (int mf = 0; mf < 4; ++mf)
            #pragma unroll
            for (int nf = 0; nf < 2; ++nf)
                #pragma unroll
                for (int kk = 0; kk < 2; ++kk)
                    acc[mf][2+nf] = __builtin_amdgcn_mfma_f32_16x16x32_bf16(
                        a0[mf][kk], b1[nf][kk], acc[mf][2+nf], 0, 0, 0);
        __builtin_amdgcn_s_setprio(0);
        __builtin_amdgcn_s_barrier();

        // ---- P3: (m-hi, n-lo)
        #pragma unroll
        for (int mf = 0; mf < 4; ++mf) { a1[mf][0] = RA(0, 4+mf, 0); a1[mf][1] = RA(0, 4+mf, 1); }
        STG_B(1, 1, tb);
        __builtin_amdgcn_s_barrier();
        __builtin_amdgcn_s_setprio(1);
        #pragma unroll
        for (int mf = 0; mf < 4; ++mf)
            #pragma unroll
            for (int nf = 0; nf < 2; ++nf)
                #pragma unroll
                for (int kk = 0; kk < 2; ++kk)
                    acc[4+mf][nf] = __builtin_amdgcn_mfma_f32_16x16x32_bf16(
                        a1[mf][kk], b0[nf][kk], acc[4+mf][nf], 0, 0, 0);
        __builtin_amdgcn_s_setprio(0);
        __builtin_amdgcn_s_barrier();

        // ---- P4: (m-hi, n-hi); end: counted vmcnt guards dbuf1
        if (p2) STG_A(0, 0, tn0);
        __builtin_amdgcn_s_barrier();
        __builtin_amdgcn_s_setprio(1);
        #pragma unroll
        for (int mf = 0; mf < 4; ++mf)
            #pragma unroll
            for (int nf = 0; nf < 2; ++nf)
                #pragma unroll
                for (int kk = 0; kk < 2; ++kk)
                    acc[4+mf][2+nf] = __builtin_amdgcn_mfma_f32_16x16x32_bf16(
                        a1[mf][kk], b1[nf][kk], acc[4+mf][2+nf], 0, 0, 0);
        __builtin_amdgcn_s_setprio(0);
        if (p2) asm volatile("s_waitcnt vmcnt(2)" ::: "memory");
        else    asm volatile("s_waitcnt vmcnt(0)" ::: "memory");
        __builtin_amdgcn_s_barrier();
        __builtin_amdgcn_sched_barrier(0);

        // ================= K-tile 2i+1 (dbuf 1) =================
        // ---- P5
        #pragma unroll
        for (int mf = 0; mf < 4; ++mf) { a0[mf][0] = RA(1, mf, 0); a0[mf][1] = RA(1, mf, 1); }
        #pragma unroll
        for (int nf = 0; nf < 2; ++nf) { b0[nf][0] = RB(1, nf, 0); b0[nf][1] = RB(1, nf, 1); }
        if (p2) STG_A(0, 1, tn0);
        __builtin_amdgcn_s_barrier();
        __builtin_amdgcn_s_setprio(1);
        #pragma unroll
        for (int mf = 0; mf < 4; ++mf)
            #pragma unroll
            for (int nf = 0; nf < 2; ++nf)
                #pragma unroll
                for (int kk = 0; kk < 2; ++kk)
                    acc[mf][nf] = __builtin_amdgcn_mfma_f32_16x16x32_bf16(
                        a0[mf][kk], b0[nf][kk], acc[mf][nf], 0, 0, 0);
        __builtin_amdgcn_s_setprio(0);
        __builtin_amdgcn_s_barrier();

        // ---- P6
        #pragma unroll
        for (int nf = 0; nf < 2; ++nf) { b1[nf][0] = RB(1, 2+nf, 0); b1[nf][1] = RB(1, 2+nf, 1); }
        if (p2) STG_B(0, 0, tn0);
        __builtin_amdgcn_s_barrier();
        __builtin_amdgcn_s_setprio(1);
        #pragma unroll
        for (int mf = 0; mf < 4; ++mf)
            #pragma unroll
            for (int nf = 0; nf < 2; ++nf)
                #pragma unroll
                for (int kk = 0; kk < 2; ++kk)
                    acc[mf][2+nf] = __builtin_amdgcn_mfma_f32_16x16x32_bf16(
                        a0[mf][kk], b1[nf][kk], acc[mf][2+nf], 0, 0, 0);
        __builtin_amdgcn_s_setprio(0);
        __builtin_amdgcn_s_barrier();

        // ---- P7
        #pragma unroll
        for (int mf = 0; mf < 4; ++mf) { a1[mf][0] = RA(1, 4+mf, 0); a1[mf][1] = RA(1, 4+mf, 1); }
        if (p2) STG_B(0, 1, tn0);
        __builtin_amdgcn_s_barrier();
        __builtin_amdgcn_s_setprio(1);
        #pragma unroll
        for (int mf = 0; mf < 4; ++mf)
            #pragma unroll
            for (int nf = 0; nf < 2; ++nf)
                #pragma unroll
                for (int kk = 0; kk < 2; ++kk)
                    acc[4+mf][nf] = __builtin_amdgcn_mfma_f32_16x16x32_bf16(
                        a1[mf][kk], b0[nf][kk], acc[4+mf][nf], 0, 0, 0);
        __builtin_amdgcn_s_setprio(0);
        __builtin_amdgcn_s_barrier();

        // ---- P8: end: counted vmcnt guards dbuf0 for next iteration's P1
        if (p3) STG_A(1, 0, tn1);
        __builtin_amdgcn_s_barrier();
        __builtin_amdgcn_s_setprio(1);
        #pragma unroll
        for (int mf = 0; mf < 4; ++mf)
            #pragma unroll
            for (int nf = 0; nf < 2; ++nf)
                #pragma unroll
                for (int kk = 0; kk < 2; ++kk)
                    acc[4+mf][2+nf] = __builtin_amdgcn_mfma_f32_16x16x32_bf16(
                        a1[mf][kk], b1[nf][kk], acc[4+mf][2+nf], 0, 0, 0);
        __builtin_amdgcn_s_setprio(0);
        if (p3) asm volatile("s_waitcnt vmcnt(2)" ::: "memory");
        else    asm volatile("s_waitcnt vmcnt(0)" ::: "memory");
        __builtin_amdgcn_s_barrier();
        __builtin_amdgcn_sched_barrier(0);
    }

    if (MODE == 2 && n0 >= 2048) {
        // V third: transpose via LDS (vm drained by tail vmcnt(0); reads done)
        #pragma unroll
        for (int ni = 0; ni < 4; ++ni) {
            int nl = wn*64 + ni*16 + l16;            // local n 0..255
            float bv = bias[n0 + nl];
            #pragma unroll
            for (int mi = 0; mi < 8; ++mi) {
                ushort4 pk;
                pk.x = f2bf(acc[mi][ni][0] + bv);
                pk.y = f2bf(acc[mi][ni][1] + bv);
                pk.z = f2bf(acc[mi][ni][2] + bv);
                pk.w = f2bf(acc[mi][ni][3] + bv);
                *(ushort4*)&Sh[nl*GTSTR + wm*128 + mi*16 + quad*4] = pk;
            }
        }
        __builtin_amdgcn_s_barrier();
        const int bb = m0 >> 11, t0 = m0 & 2047;
        #pragma unroll
        for (int p = 0; p < 16; ++p) {
            int c = p*512 + tid;
            int row = c >> 5, ch = c & 31;           // row: local n, ch: 8-short m-chunk
            int nv = n0 + row - 2048;
            int hv = nv >> 6, dv = nv & 63;
            *(uint4*)&((unsigned short*)Cout2)[((size_t)((bb*16 + hv)*64 + dv))*2048 + t0 + ch*8] =
                *(uint4*)&Sh[row*GTSTR + ch*8];
        }
        return;
    }

    const int cstride = (MODE == 2) ? 2048 : N;
    #pragma unroll
    for (int ni = 0; ni < 4; ++ni) {
        int n = n0 + wn*64 + ni*16 + l16;
        float bv = bias[n];
        #pragma unroll
        for (int mi = 0; mi < 8; ++mi) {
            #pragma unroll
            for (int r = 0; r < 4; ++r) {
                int m = m0 + wm*128 + mi*16 + quad*4 + r;
                float val = acc[mi][ni][r] + bv;
                if (MODE == 1)
                    ((float*)Cout)[(size_t)m*cstride + n] = val;
                else
                    ((unsigned short*)Cout)[(size_t)m*cstride + n] = f2bf(val);
            }
        }
    }
}

// ---------------- big-tile MFMA bf16 GEMM (round-6 structure, out-proj) --------
template <int MODE, int BM, int BN>
__global__ __launch_bounds__(512, 2) void gemm_big(
    const unsigned short* __restrict__ A, const unsigned short* __restrict__ BT,
    const float* __restrict__ bias, void* __restrict__ Cout, void* __restrict__ Cout2,
    int K, int N, int NXT)
{
    constexpr int SHSZ = 2*(BM+BN)*64;               // shorts; 96 KB
    __shared__ __align__(16) unsigned short Sh[SHSZ];

    const int tid  = threadIdx.x;
    const int lane = tid & 63;
    const int wave = tid >> 6;                       // 0..7
    constexpr int WNG = BN/64;                       // waves along n
    const int wm = wave / WNG, wn = wave % WNG;
    const int quad = lane >> 4, l16 = lane & 15;

    const int nwg = gridDim.x, cpx = nwg >> 3;
    const int wg = (blockIdx.x & 7)*cpx + (blockIdx.x >> 3);
    const int by = wg / NXT, bx = wg - by*NXT;
    const int m0 = by*BM, n0 = bx*BN;

    f32x4 acc[4][4] = {};
    const int nk = K >> 6;

    auto STAGE = [&](int t, int buf) {
        const int k0 = t << 6;
        unsigned short* Ab = &Sh[buf*(BM*64)];
        unsigned short* Bb = &Sh[2*BM*64 + buf*(BN*64)];
        #pragma unroll
        for (int p = 0; p < BM/64; ++p) {
            int c = p*512 + tid;
            int row = c >> 3, ch = (c & 7) ^ (row & 7);
            GLOAD_LDS16(&A[(size_t)(m0 + row)*K + k0 + ch*8], &Ab[c*8]);
        }
        #pragma unroll
        for (int p = 0; p < BN/64; ++p) {
            int c = p*512 + tid;
            int row = c >> 3, ch = (c & 7) ^ (row & 7);
            GLOAD_LDS16(&BT[(size_t)(n0 + row)*K + k0 + ch*8], &Bb[c*8]);
        }
    };

    STAGE(0, 0);
    STAGE(1, 1);

    for (int t = 0; t < nk; ++t) {
        const int buf = t & 1;
        const unsigned short* Ab = &Sh[buf*(BM*64)];
        const unsigned short* Bb = &Sh[2*BM*64 + buf*(BN*64)];

        if (t == nk - 1) asm volatile("s_waitcnt vmcnt(0)" ::: "memory");
        else             asm volatile("s_waitcnt vmcnt(6)" ::: "memory");
        __builtin_amdgcn_s_barrier();
        __builtin_amdgcn_sched_barrier(0);           // no ds_read hoists above

        short8 fa[4][2], fb[2][2];

        // ---- phase 0: all m x n-lo
        #pragma unroll
        for (int mi = 0; mi < 4; ++mi)
            #pragma unroll
            for (int kk = 0; kk < 2; ++kk) {
                int row = wm*64 + mi*16 + l16;
                fa[mi][kk] = *(const short8*)&Ab[row*64 + (((kk*4 + quad) ^ (row & 7))*8)];
            }
        #pragma unroll
        for (int ni = 0; ni < 2; ++ni)
            #pragma unroll
            for (int kk = 0; kk < 2; ++kk) {
                int row = wn*64 + ni*16 + l16;
                fb[ni][kk] = *(const short8*)&Bb[row*64 + (((kk*4 + quad) ^ (row & 7))*8)];
            }
        __builtin_amdgcn_s_barrier();
        __builtin_amdgcn_s_setprio(1);
        #pragma unroll
        for (int mi = 0; mi < 4; ++mi)
            #pragma unroll
            for (int ni = 0; ni < 2; ++ni)
                #pragma unroll
                for (int kk = 0; kk < 2; ++kk)
                    acc[mi][ni] = __builtin_amdgcn_mfma_f32_16x16x32_bf16(
                        fa[mi][kk], fb[ni][kk], acc[mi][ni], 0, 0, 0);
        __builtin_amdgcn_s_setprio(0);
        __builtin_amdgcn_s_barrier();

        // ---- phase 1: all m x n-hi
        #pragma unroll
        for (int ni = 0; ni < 2; ++ni)
            #pragma unroll
            for (int kk = 0; kk < 2; ++kk) {
                int row = wn*64 + 32 + ni*16 + l16;
                fb[ni][kk] = *(const short8*)&Bb[row*64 + (((kk*4 + quad) ^ (row & 7))*8)];
            }
        __builtin_amdgcn_s_barrier();
        __builtin_amdgcn_s_setprio(1);
        #pragma unroll
        for (int mi = 0; mi < 4; ++mi)
            #pragma unroll
            for (int ni = 0; ni < 2; ++ni)
                #pragma unroll
                for (int kk = 0; kk < 2; ++kk)
                    acc[mi][2 + ni] = __builtin_amdgcn_mfma_f32_16x16x32_bf16(
                        fa[mi][kk], fb[ni][kk], acc[mi][2 + ni], 0, 0, 0);
        __builtin_amdgcn_s_setprio(0);
        __builtin_amdgcn_s_barrier();                // all buf-t reads consumed

        __builtin_amdgcn_sched_barrier(0);           // STAGE must not hoist above
        if (t + 2 < nk) STAGE(t + 2, buf);           // prefetch 2 tiles ahead
    }

    const int cstride = (MODE == 2) ? 2048 : N;
    #pragma unroll
    for (int ni = 0; ni < 4; ++ni) {
        int n = n0 + wn*64 + ni*16 + l16;
        float bv = bias[n];
        #pragma unroll
        for (int mi = 0; mi < 4; ++mi) {
            #pragma unroll
            for (int r = 0; r < 4; ++r) {
                int m = m0 + wm*64 + mi*16 + quad*4 + r;
                float val = acc[mi][ni][r] + bv;
                if (MODE == 1)
                    ((float*)Cout)[(size_t)m*cstride + n] = val;
                else
                    ((unsigned short*)Cout)[(size_t)m*cstride + n] = f2bf(val);
            }
        }
    }
}

// ---------------- MFMA flash attention: 4-wave block, one q-chunk, grid 1024 ----
// Round-8 post-mortem: attn VALU-DEPENDENCY-bound — VALUBusy 52% at only
// 1.5 waves/SIMD (occupancy 19%). Residency was capped by GRID (512 = exactly
// 2 blocks/CU), not LDS (50KB -> 3/CU fits) nor VGPR ((256,3)=170 fits).
// This round: un-pair the q-chunks -> grid 1024, one 128-row chunk per block,
// 3 blocks/CU resident (12 waves/CU). Dispatch order = DESCENDING qc
// (qc = 15-(j>>3)): long blocks (32 tiles) launch first, the 256 short ones
// (qc<=3) backfill freed slots -> per-CU work ~68 tiles over 3 slots.
// Per-tile code unchanged (best measured). XCD pinning i&7 kept.
#define PST 72
__global__ __launch_bounds__(256, 3) void attn_mfma(
    const unsigned short* __restrict__ QK, const unsigned short* __restrict__ VT,
    unsigned short* __restrict__ Y)
{
    // LDS: K dbuf 2x4096 shorts, V dbuf 2x4096 shorts, P 4 waves x 32 x PST
    __shared__ __align__(16) unsigned short Sh[16384 + 4*32*PST];

    const int tid  = threadIdx.x;
    const int lane = tid & 63;
    const int wave = tid >> 6;
    const int quad = lane >> 4, l16 = lane & 15;

    const int i = blockIdx.x;            // 0..1023
    const int xcd = i & 7, j = i >> 3;   // j 0..127
    const int qc = 15 - (j >> 3);        // descending: longest blocks first
    const int u = j & 7;                 // bh-group 0..7
    const int bh2 = xcd + 8*u;
    const int b = bh2 >> 4, h = bh2 & 15;
    const size_t qkbase = (size_t)(b*TT) * 2048;
    const size_t vbase  = (size_t)(bh2*64) * 2048;
    const int qcol = h*64, kcol = 1024 + h*64;
    const float C2 = 0.18033688011112042f;   // (1/sqrt(64)) * log2(e)

    unsigned short* Pw = &Sh[16384 + wave*(32*PST)];

    const int nkt = 2*qc + 2;            // k-tiles for this chunk
    const int q0w = qc*128 + wave*32;    // this wave's q-row base

    // Q fragments straight from global (held for the whole loop)
    short8 aq[2][2];
    #pragma unroll
    for (int mt = 0; mt < 2; ++mt)
        #pragma unroll
        for (int kk = 0; kk < 2; ++kk)
            aq[mt][kk] = *(const short8*)&QK[qkbase + (size_t)(q0w + mt*16 + l16)*2048
                                            + qcol + kk*32 + quad*8];

    f32x4 o[2][4] = {};
    float mold[2][4], lsum[2][4];
    #pragma unroll
    for (int mt = 0; mt < 2; ++mt)
        #pragma unroll
        for (int r = 0; r < 4; ++r) { mold[mt][r] = -3.0e38f; lsum[mt][r] = 0.0f; }

    auto STAGE = [&](int buf, int k0) {
        unsigned short* Kb = &Sh[buf*4096];
        unsigned short* Vb = &Sh[8192 + buf*4096];
        #pragma unroll
        for (int p = 0; p < 2; ++p) {
            int c = p*256 + tid;               // 16B chunk index, linear in lane
            int r = c >> 3;
            int ch = (c & 7) ^ (r & 7);        // source chunk (inverse swizzle)
            GLOAD_LDS16(&QK[qkbase + (size_t)(k0 + r)*2048 + kcol + ch*8], &Kb[c*8]);
        }
        #pragma unroll
        for (int p = 0; p < 2; ++p) {
            int c = p*256 + tid;
            int r = c >> 3;                    // r = head-dim row of VT
            int ch = (c & 7) ^ (r & 7);
            GLOAD_LDS16(&VT[vbase + (size_t)r*2048 + k0 + ch*8], &Vb[c*8]);
        }
    };

    STAGE(0, 0);
    asm volatile("s_waitcnt vmcnt(0)" ::: "memory");
    __builtin_amdgcn_s_barrier();

    int cur = 0;
    for (int t = 0; t < nkt; ++t) {
        const int k0 = t * 64;
        if (t + 1 < nkt) STAGE(cur ^ 1, (t + 1) * 64);   // async prefetch

        if (k0 <= q0w + 31) {                  // wave-uniform causal activity guard
            const unsigned short* Kb = &Sh[cur*4096];
            const unsigned short* Vb = &Sh[8192 + cur*4096];

            // ---- S = Q K^T from LDS (swizzled reads)
            f32x4 s[2][4];
            #pragma unroll
            for (int nt = 0; nt < 4; ++nt) {
                if (k0 + nt*16 <= q0w + 31) {
                    f32x4 z = {};
                    s[0][nt] = z; s[1][nt] = z;
                    #pragma unroll
                    for (int kk = 0; kk < 2; ++kk) {
                        int r = nt*16 + l16;
                        short8 bk = *(const short8*)&Kb[r*64 + (((kk*4 + quad) ^ (r & 7))*8)];
                        s[0][nt] = __builtin_amdgcn_mfma_f32_16x16x32_bf16(aq[0][kk], bk, s[0][nt], 0, 0, 0);
                        s[1][nt] = __builtin_amdgcn_mfma_f32_16x16x32_bf16(aq[1][kk], bk, s[1][nt], 0, 0, 0);
                    }
                } else {
                    #pragma unroll
                    for (int r = 0; r < 4; ++r) { s[0][nt][r] = -3.0e38f; s[1][nt][r] = -3.0e38f; }
                }
            }

            // ---- issue V-frag LDS loads now; latency hides under softmax
            short8 bv[2][4];
            #pragma unroll
            for (int kk = 0; kk < 2; ++kk)
                #pragma unroll
                for (int dt = 0; dt < 4; ++dt) {
                    int r = dt*16 + l16;
                    bv[kk][dt] = *(const short8*)&Vb[r*64 + (((kk*4 + quad) ^ (r & 7))*8)];
                }

            // ---- element causal mask (straddling tiles only)
            if (k0 + 63 > q0w) {
                #pragma unroll
                for (int mt = 0; mt < 2; ++mt)
                    #pragma unroll
                    for (int nt = 0; nt < 4; ++nt)
                        #pragma unroll
                        for (int r = 0; r < 4; ++r) {
                            int kg = k0 + nt*16 + l16;
                            int qg = q0w + mt*16 + quad*4 + r;
                            if (kg > qg) s[mt][nt][r] = -3.0e38f;
                        }
            }

            // ---- online softmax (exp2 domain), DPP reductions
            float m2n[2][4], al[2][4];
            #pragma unroll
            for (int mt = 0; mt < 2; ++mt)
                #pragma unroll
                for (int r = 0; r < 4; ++r) {
                    float rm = fmaxf(fmaxf(s[mt][0][r], s[mt][1][r]),
                                     fmaxf(s[mt][2][r], s[mt][3][r]));
                    rm = red_max16(rm);
                    float m2 = fmaxf(mold[mt][r], rm * C2);
                    al[mt][r]  = EXP2(mold[mt][r] - m2);
                    m2n[mt][r] = m2;
                }
            float rs[2][4] = {};
            #pragma unroll
            for (int mt = 0; mt < 2; ++mt)
                #pragma unroll
                for (int nt = 0; nt < 4; ++nt)
                    #pragma unroll
                    for (int r = 0; r < 4; ++r) {
                        float p = EXP2(fmaf(s[mt][nt][r], C2, -m2n[mt][r]));
                        s[mt][nt][r] = p;
                        rs[mt][r] += p;
                    }
            #pragma unroll
            for (int mt = 0; mt < 2; ++mt)
                #pragma unroll
                for (int r = 0; r < 4; ++r) {
                    float tsum = red_sum16(rs[mt][r]);
                    lsum[mt][r] = lsum[mt][r]*al[mt][r] + tsum;
                    mold[mt][r] = m2n[mt][r];
                }

            // ---- P -> LDS (wave-private buffer; same-wave RAW, no barrier)
            #pragma unroll
            for (int mt = 0; mt < 2; ++mt)
                #pragma unroll
                for (int nt = 0; nt < 4; ++nt)
                    #pragma unroll
                    for (int r = 0; r < 4; ++r) {
                        union { float f; uint32_t u; } c; c.f = s[mt][nt][r];
                        Pw[(mt*16 + quad*4 + r)*PST + nt*16 + l16] =
                            (unsigned short)((c.u + 0x8000u) >> 16);
                    }

            // ---- O = O*alpha + P V
            #pragma unroll
            for (int mt = 0; mt < 2; ++mt)
                #pragma unroll
                for (int dt = 0; dt < 4; ++dt)
                    #pragma unroll
                    for (int r = 0; r < 4; ++r)
                        o[mt][dt][r] *= al[mt][r];
            #pragma unroll
            for (int kk = 0; kk < 2; ++kk) {
                short8 ap0 = *(short8*)&Pw[(     l16)*PST + kk*32 + quad*8];
                short8 ap1 = *(short8*)&Pw[(16 + l16)*PST + kk*32 + quad*8];
                #pragma unroll
                for (int dt = 0; dt < 4; ++dt) {
                    o[0][dt] = __builtin_amdgcn_mfma_f32_16x16x32_bf16(ap0, bv[kk][dt], o[0][dt], 0, 0, 0);
                    o[1][dt] = __builtin_amdgcn_mfma_f32_16x16x32_bf16(ap1, bv[kk][dt], o[1][dt], 0, 0, 0);
                }
            }
        }

        asm volatile("s_waitcnt vmcnt(0)" ::: "memory");  // next-tile stage landed
        __builtin_amdgcn_s_barrier();                     // all waves' stage + reads done
        cur ^= 1;
    }

    // ---- normalize + store (bf16 intermediate Y)
    #pragma unroll
    for (int mt = 0; mt < 2; ++mt)
        #pragma unroll
        for (int r = 0; r < 4; ++r) {
            float inv = 1.0f / lsum[mt][r];
            int tq = q0w + mt*16 + quad*4 + r;
            #pragma unroll
            for (int dt = 0; dt < 4; ++dt)
                Y[((size_t)(b*TT + tq))*DD + h*64 + dt*16 + l16] = f2bf(o[mt][dt][r] * inv);
        }
}

extern "C" void kernel_launch(void* const* d_in, const int* in_sizes, int n_in,
                              void* d_out, int out_size, void* d_ws, size_t ws_size,
                              hipStream_t stream)
{
    const float* x    = (const float*)d_in[0];   // [4,2048,1024] fp32
    // d_in[1] = causal_mask (int32) — causality implemented analytically, unused
    const float* wqkv = (const float*)d_in[2];   // [1024][3072] fp32
    const float* bqkv = (const float*)d_in[3];   // [3072] fp32
    const float* wout = (const float*)d_in[4];   // [1024][1024] fp32
    const float* bout = (const float*)d_in[5];   // [1024] fp32
    float* out = (float*)d_out;                  // [4,2048,1024] fp32

    char* ws = (char*)d_ws;
    unsigned short* Xb    = (unsigned short*)ws;                    // 16 MB
    unsigned short* WqkvT = (unsigned short*)(ws + 16777216);       // 6 MB
    unsigned short* WoutT = (unsigned short*)(ws + 23068672);       // 2 MB
    unsigned short* QK    = (unsigned short*)(ws + 25165824);       // 32 MB [M][2048]
    unsigned short* VTb   = (unsigned short*)(ws + 58720256);       // 16 MB [(bh*64+d)][2048]
    unsigned short* Ybuf  = (unsigned short*)(ws + 75497472);       // 16 MB

    cvt_f32_bf16<<<(M1*KDIM/4 + 255)/256, 256, 0, stream>>>(x, Xb, M1*KDIM/4);
    transpose_f32_bf16<<<dim3(N1/32, KDIM/32), dim3(32, 8), 0, stream>>>(wqkv, WqkvT, KDIM, N1);
    transpose_f32_bf16<<<dim3(DD/32, KDIM/32), dim3(32, 8), 0, stream>>>(wout, WoutT, KDIM, DD);
    gemm8p<2><<<dim3(384), 512, 0, stream>>>(Xb, WqkvT, bqkv, QK, VTb, KDIM, N1, 12);
    attn_mfma<<<dim3(1024), 256, 0, stream>>>(QK, VTb, Ybuf);
    gemm_big<1, 128, 256><<<dim3(256), 512, 0, stream>>>(Ybuf, WoutT, bout, out, nullptr, KDIM, DD, 4);
}

// Round 10
// 288.234 us; speedup vs baseline: 1.1233x; 1.0149x over previous
//
#include <hip/hip_runtime.h>
#include <hip/hip_bf16.h>
#include <stdint.h>

// Problem constants
#define BB 4
#define TT 2048
#define DD 1024
#define HH 16
#define HDD 64
// derived
#define M1 (BB*TT)      // 8192 rows
#define N1 (3*DD)       // 3072
#define KDIM DD         // 1024

typedef __attribute__((ext_vector_type(8))) short short8;   // 8 bf16 MFMA operand
typedef __attribute__((ext_vector_type(4))) float f32x4;

#if __has_builtin(__builtin_amdgcn_exp2f)
#define EXP2(x) __builtin_amdgcn_exp2f(x)
#else
#define EXP2(x) exp2f(x)
#endif

// async global->LDS, 16B per lane (global_load_lds_dwordx4)
#define GLOAD_LDS16(gp, lp) \
    __builtin_amdgcn_global_load_lds( \
        (const __attribute__((address_space(1))) void*)(gp), \
        (__attribute__((address_space(3))) void*)(lp), 16, 0, 0)

__device__ __forceinline__ float bf2f(unsigned short u) {
    union { uint32_t u32; float f; } c; c.u32 = ((uint32_t)u) << 16; return c.f;
}
__device__ __forceinline__ unsigned short f2bf(float f) {
    union { float f; uint32_t u32; } c; c.f = f;
    uint32_t u = c.u32;
    return (unsigned short)((u + 0x7FFFu + ((u >> 16) & 1u)) >> 16);  // RNE
}

// DPP row_ror rotate-reduce within the 16-lane DPP row.
template <int CTRL>
__device__ __forceinline__ float dpp_ror(float x) {
    union { float f; int i; } u, r;
    u.f = x;
    r.i = __builtin_amdgcn_update_dpp(u.i, u.i, CTRL, 0xF, 0xF, false);
    return r.f;
}
__device__ __forceinline__ float red_max16(float x) {
    x = fmaxf(x, dpp_ror<0x128>(x));   // row_ror:8
    x = fmaxf(x, dpp_ror<0x124>(x));   // row_ror:4
    x = fmaxf(x, dpp_ror<0x122>(x));   // row_ror:2
    x = fmaxf(x, dpp_ror<0x121>(x));   // row_ror:1
    return x;
}
__device__ __forceinline__ float red_sum16(float x) {
    x += dpp_ror<0x128>(x);
    x += dpp_ror<0x124>(x);
    x += dpp_ror<0x122>(x);
    x += dpp_ror<0x121>(x);
    return x;
}

// 2 f32 -> packed 2x bf16 (RNE) in one VALU op. No builtin on gfx950 (m240);
// inline asm is a genuine win here: replaces a MANUAL add+lshr pack the
// compiler cannot fuse. Stores stay compiler-managed (no asm LDS hazards).
__device__ __forceinline__ uint32_t cvt_pk_bf16(float lo, float hi) {
    uint32_t u;
    asm("v_cvt_pk_bf16_f32 %0, %1, %2" : "=v"(u) : "v"(lo), "v"(hi));
    return u;
}

// ---------------- elementwise fp32 -> bf16 (x), 4 elems/thread ----------------
__global__ __launch_bounds__(256) void cvt_f32_bf16(
    const float* __restrict__ in, unsigned short* __restrict__ out, int n4)
{
    int i = blockIdx.x * 256 + threadIdx.x;
    if (i >= n4) return;
    float4 v = *(const float4*)&in[(size_t)i * 4];
    ushort4 o;
    o.x = f2bf(v.x); o.y = f2bf(v.y); o.z = f2bf(v.z); o.w = f2bf(v.w);
    *(ushort4*)&out[(size_t)i * 4] = o;
}

// ---------------- transpose+convert: in fp32 [R][C] -> out bf16 [C][R] ----------------
__global__ __launch_bounds__(256) void transpose_f32_bf16(
    const float* __restrict__ in, unsigned short* __restrict__ out,
    int R, int C)
{
    __shared__ unsigned short tile[32][33];
    int bx = blockIdx.x;
    int by = blockIdx.y;
    int x = bx*32 + threadIdx.x;
    int y0 = by*32 + threadIdx.y;
    #pragma unroll
    for (int i = 0; i < 32; i += 8)
        tile[threadIdx.y + i][threadIdx.x] = f2bf(in[(size_t)(y0 + i)*C + x]);
    __syncthreads();
    int xo = by*32 + threadIdx.x;
    int yo = bx*32 + threadIdx.y;
    #pragma unroll
    for (int i = 0; i < 32; i += 8)
        out[(size_t)(yo + i)*R + xo] = tile[threadIdx.x][threadIdx.y + i];
}

// ---------------- QKV GEMM: m201 8-phase 256x256 (round-8, best measured) -------
#define GTSTR 264
template <int MODE>
__global__ __launch_bounds__(512, 2) void gemm8p(
    const unsigned short* __restrict__ A, const unsigned short* __restrict__ BT,
    const float* __restrict__ bias, void* __restrict__ Cout, void* __restrict__ Cout2,
    int K, int N, int NXT)
{
    constexpr int SHSZ = (MODE == 2) ? 256*GTSTR : 65536;   // >= 65536 shorts
    __shared__ __align__(16) unsigned short Sh[SHSZ];

    const int tid  = threadIdx.x;
    const int lane = tid & 63;
    const int wave = tid >> 6;               // 0..7
    const int wm = wave >> 2, wn = wave & 3; // 2m x 4n
    const int quad = lane >> 4, l16 = lane & 15;

    const int nwg = gridDim.x, cpx = nwg >> 3;
    const int wg = (blockIdx.x & 7)*cpx + (blockIdx.x >> 3);
    const int by = wg / NXT, bx = wg - by*NXT;
    const int m0 = by*256, n0 = bx*256;

    f32x4 acc[8][4] = {};
    const int nk = K >> 6;                   // 16

    auto SA = [&](int d, int h) -> unsigned short* { return &Sh[(d*2 + h)*16384]; };
    auto SB = [&](int d, int h) -> unsigned short* { return &Sh[(d*2 + h)*16384 + 8192]; };

    auto STG_A = [&](int d, int h, int t) {
        const int k0 = t << 6;
        unsigned short* dst = SA(d, h);
        #pragma unroll
        for (int p = 0; p < 2; ++p) {
            int c = p*512 + tid;
            int rl = c >> 3, ch = (c & 7) ^ (rl & 7);
            GLOAD_LDS16(&A[(size_t)(m0 + h*128 + rl)*K + k0 + ch*8], &dst[c*8]);
        }
    };
    auto STG_B = [&](int d, int h, int t) {
        const int k0 = t << 6;
        unsigned short* dst = SB(d, h);
        #pragma unroll
        for (int p = 0; p < 2; ++p) {
            int c = p*512 + tid;
            int rl = c >> 3, ch = (c & 7) ^ (rl & 7);
            GLOAD_LDS16(&BT[(size_t)(n0 + h*128 + rl)*K + k0 + ch*8], &dst[c*8]);
        }
    };
    auto RA = [&](int d, int mf, int kk) -> short8 {
        int rl = mf*16 + l16;                              // within half wm
        return *(const short8*)&SA(d, wm)[rl*64 + (((kk*4 + quad) ^ (rl & 7))*8)];
    };
    auto RB = [&](int d, int nf, int kk) -> short8 {
        int rl = (wn & 1)*64 + nf*16 + l16;                // within half wn>>1
        return *(const short8*)&SB(d, wn >> 1)[rl*64 + (((kk*4 + quad) ^ (rl & 7))*8)];
    };

    // prologue: tile0 all 4 halves -> dbuf0; tile1 A0 -> dbuf1
    STG_A(0, 0, 0); STG_A(0, 1, 0); STG_B(0, 0, 0); STG_B(0, 1, 0);
    STG_A(1, 0, 1);
    asm volatile("s_waitcnt vmcnt(2)" ::: "memory");       // dbuf0 landed
    __builtin_amdgcn_s_barrier();
    __builtin_amdgcn_sched_barrier(0);

    for (int i = 0; i < nk/2; ++i) {
        const int tb = 2*i + 1, tn0 = 2*i + 2, tn1 = 2*i + 3;
        const bool p2 = (tn0 < nk), p3 = (tn1 < nk);
        short8 a0[4][2], a1[4][2], b0[2][2], b1[2][2];

        // ================= K-tile 2i (dbuf 0) =================
        // ---- P1: (m-lo, n-lo)
        #pragma unroll
        for (int mf = 0; mf < 4; ++mf) { a0[mf][0] = RA(0, mf, 0); a0[mf][1] = RA(0, mf, 1); }
        #pragma unroll
        for (int nf = 0; nf < 2; ++nf) { b0[nf][0] = RB(0, nf, 0); b0[nf][1] = RB(0, nf, 1); }
        STG_A(1, 1, tb);
        __builtin_amdgcn_s_barrier();
        __builtin_amdgcn_s_setprio(1);
        #pragma unroll
        for (int mf = 0; mf < 4; ++mf)
            #pragma unroll
            for (int nf = 0; nf < 2; ++nf)
                #pragma unroll
                for (int kk = 0; kk < 2; ++kk)
                    acc[mf][nf] = __builtin_amdgcn_mfma_f32_16x16x32_bf16(
                        a0[mf][kk], b0[nf][kk], acc[mf][nf], 0, 0, 0);
        __builtin_amdgcn_s_setprio(0);
        __builtin_amdgcn_s_barrier();

        // ---- P2: (m-lo, n-hi)
        #pragma unroll
        for (int nf = 0; nf < 2; ++nf) { b1[nf][0] = RB(0, 2+nf, 0); b1[nf][1] = RB(0, 2+nf, 1); }
        STG_B(1, 0, tb);
        __builtin_amdgcn_s_barrier();
        __builtin_amdgcn_s_setprio(1);
        #pragma unroll
        for (int mf = 0; mf < 4; ++mf)
            #pragma unroll
            for (int nf = 0; nf < 2; ++nf)
                #pragma unroll
                for (int kk = 0; kk < 2; ++kk)
                    acc[mf][2+nf] = __builtin_amdgcn_mfma_f32_16x16x32_bf16(
                        a0[mf][kk], b1[nf][kk], acc[mf][2+nf], 0, 0, 0);
        __builtin_amdgcn_s_setprio(0);
        __builtin_amdgcn_s_barrier();

        // ---- P3: (m-hi, n-lo)
        #pragma unroll
        for (int mf = 0; mf < 4; ++mf) { a1[mf][0] = RA(0, 4+mf, 0); a1[mf][1] = RA(0, 4+mf, 1); }
        STG_B(1, 1, tb);
        __builtin_amdgcn_s_barrier();
        __builtin_amdgcn_s_setprio(1);
        #pragma unroll
        for (int mf = 0; mf < 4; ++mf)
            #pragma unroll
            for (int nf = 0; nf < 2; ++nf)
                #pragma unroll
                for (int kk = 0; kk < 2; ++kk)
                    acc[4+mf][nf] = __builtin_amdgcn_mfma_f32_16x16x32_bf16(
                        a1[mf][kk], b0[nf][kk], acc[4+mf][nf], 0, 0, 0);
        __builtin_amdgcn_s_setprio(0);
        __builtin_amdgcn_s_barrier();

        // ---- P4: (m-hi, n-hi); end: counted vmcnt guards dbuf1
        if (p2) STG_A(0, 0, tn0);
        __builtin_amdgcn_s_barrier();
        __builtin_amdgcn_s_setprio(1);
        #pragma unroll
        for (int mf = 0; mf < 4; ++mf)
            #pragma unroll
            for (int nf = 0; nf < 2; ++nf)
                #pragma unroll
                for (int kk = 0; kk < 2; ++kk)
                    acc[4+mf][2+nf] = __builtin_amdgcn_mfma_f32_16x16x32_bf16(
                        a1[mf][kk], b1[nf][kk], acc[4+mf][2+nf], 0, 0, 0);
        __builtin_amdgcn_s_setprio(0);
        if (p2) asm volatile("s_waitcnt vmcnt(2)" ::: "memory");
        else    asm volatile("s_waitcnt vmcnt(0)" ::: "memory");
        __builtin_amdgcn_s_barrier();
        __builtin_amdgcn_sched_barrier(0);

        // ================= K-tile 2i+1 (dbuf 1) =================
        // ---- P5
        #pragma unroll
        for (int mf = 0; mf < 4; ++mf) { a0[mf][0] = RA(1, mf, 0); a0[mf][1] = RA(1, mf, 1); }
        #pragma unroll
        for (int nf = 0; nf < 2; ++nf) { b0[nf][0] = RB(1, nf, 0); b0[nf][1] = RB(1, nf, 1); }
        if (p2) STG_A(0, 1, tn0);
        __builtin_amdgcn_s_barrier();
        __builtin_amdgcn_s_setprio(1);
        #pragma unroll
        for (int mf = 0; mf < 4; ++mf)
            #pragma unroll
            for (int nf = 0; nf < 2; ++nf)
                #pragma unroll
                for (int kk = 0; kk < 2; ++kk)
                    acc[mf][nf] = __builtin_amdgcn_mfma_f32_16x16x32_bf16(
                        a0[mf][kk], b0[nf][kk], acc[mf][nf], 0, 0, 0);
        __builtin_amdgcn_s_setprio(0);
        __builtin_amdgcn_s_barrier();

        // ---- P6
        #pragma unroll
        for (int nf = 0; nf < 2; ++nf) { b1[nf][0] = RB(1, 2+nf, 0); b1[nf][1] = RB(1, 2+nf, 1); }
        if (p2) STG_B(0, 0, tn0);
        __builtin_amdgcn_s_barrier();
        __builtin_amdgcn_s_setprio(1);
        #pragma unroll
        for (int mf = 0; mf < 4; ++mf)
            #pragma unroll
            for (int nf = 0; nf < 2; ++nf)
                #pragma unroll
                for (int kk = 0; kk < 2; ++kk)
                    acc[mf][2+nf] = __builtin_amdgcn_mfma_f32_16x16x32_bf16(
                        a0[mf][kk], b1[nf][kk], acc[mf][2+nf], 0, 0, 0);
        __builtin_amdgcn_s_setprio(0);
        __builtin_amdgcn_s_barrier();

        // ---- P7
        #pragma unroll
        for (int mf = 0; mf < 4; ++mf) { a1[mf][0] = RA(1, 4+mf, 0); a1[mf][1] = RA(1, 4+mf, 1); }
        if (p2) STG_B(0, 1, tn0);
        __builtin_amdgcn_s_barrier();
        __builtin_amdgcn_s_setprio(1);
        #pragma unroll
        for (int mf = 0; mf < 4; ++mf)
            #pragma unroll
            for (int nf = 0; nf < 2; ++nf)
                #pragma unroll
                for (int kk = 0; kk < 2; ++kk)
                    acc[4+mf][nf] = __builtin_amdgcn_mfma_f32_16x16x32_bf16(
                        a1[mf][kk], b0[nf][kk], acc[4+mf][nf], 0, 0, 0);
        __builtin_amdgcn_s_setprio(0);
        __builtin_amdgcn_s_barrier();

        // ---- P8: end: counted vmcnt guards dbuf0 for next iteration's P1
        if (p3) STG_A(1, 0, tn1);
        __builtin_amdgcn_s_barrier();
        __builtin_amdgcn_s_setprio(1);
        #pragma unroll
        for (int mf = 0; mf < 4; ++mf)
            #pragma unroll
            for (int nf = 0; nf < 2; ++nf)
                #pragma unroll
                for (int kk = 0; kk < 2; ++kk)
                    acc[4+mf][2+nf] = __builtin_amdgcn_mfma_f32_16x16x32_bf16(
                        a1[mf][kk], b1[nf][kk], acc[4+mf][2+nf], 0, 0, 0);
        __builtin_amdgcn_s_setprio(0);
        if (p3) asm volatile("s_waitcnt vmcnt(2)" ::: "memory");
        else    asm volatile("s_waitcnt vmcnt(0)" ::: "memory");
        __builtin_amdgcn_s_barrier();
        __builtin_amdgcn_sched_barrier(0);
    }

    if (MODE == 2 && n0 >= 2048) {
        // V third: transpose via LDS (vm drained by tail vmcnt(0); reads done)
        #pragma unroll
        for (int ni = 0; ni < 4; ++ni) {
            int nl = wn*64 + ni*16 + l16;            // local n 0..255
            float bv = bias[n0 + nl];
            #pragma unroll
            for (int mi = 0; mi < 8; ++mi) {
                ushort4 pk;
                pk.x = f2bf(acc[mi][ni][0] + bv);
                pk.y = f2bf(acc[mi][ni][1] + bv);
                pk.z = f2bf(acc[mi][ni][2] + bv);
                pk.w = f2bf(acc[mi][ni][3] + bv);
                *(ushort4*)&Sh[nl*GTSTR + wm*128 + mi*16 + quad*4] = pk;
            }
        }
        __builtin_amdgcn_s_barrier();
        const int bb = m0 >> 11, t0 = m0 & 2047;
        #pragma unroll
        for (int p = 0; p < 16; ++p) {
            int c = p*512 + tid;
            int row = c >> 5, ch = c & 31;           // row: local n, ch: 8-short m-chunk
            int nv = n0 + row - 2048;
            int hv = nv >> 6, dv = nv & 63;
            *(uint4*)&((unsigned short*)Cout2)[((size_t)((bb*16 + hv)*64 + dv))*2048 + t0 + ch*8] =
                *(uint4*)&Sh[row*GTSTR + ch*8];
        }
        return;
    }

    const int cstride = (MODE == 2) ? 2048 : N;
    #pragma unroll
    for (int ni = 0; ni < 4; ++ni) {
        int n = n0 + wn*64 + ni*16 + l16;
        float bv = bias[n];
        #pragma unroll
        for (int mi = 0; mi < 8; ++mi) {
            #pragma unroll
            for (int r = 0; r < 4; ++r) {
                int m = m0 + wm*128 + mi*16 + quad*4 + r;
                float val = acc[mi][ni][r] + bv;
                if (MODE == 1)
                    ((float*)Cout)[(size_t)m*cstride + n] = val;
                else
                    ((unsigned short*)Cout)[(size_t)m*cstride + n] = f2bf(val);
            }
        }
    }
}

// ---------------- big-tile MFMA bf16 GEMM (round-6 structure, out-proj) --------
template <int MODE, int BM, int BN>
__global__ __launch_bounds__(512, 2) void gemm_big(
    const unsigned short* __restrict__ A, const unsigned short* __restrict__ BT,
    const float* __restrict__ bias, void* __restrict__ Cout, void* __restrict__ Cout2,
    int K, int N, int NXT)
{
    constexpr int SHSZ = 2*(BM+BN)*64;               // shorts; 96 KB
    __shared__ __align__(16) unsigned short Sh[SHSZ];

    const int tid  = threadIdx.x;
    const int lane = tid & 63;
    const int wave = tid >> 6;                       // 0..7
    constexpr int WNG = BN/64;                       // waves along n
    const int wm = wave / WNG, wn = wave % WNG;
    const int quad = lane >> 4, l16 = lane & 15;

    const int nwg = gridDim.x, cpx = nwg >> 3;
    const int wg = (blockIdx.x & 7)*cpx + (blockIdx.x >> 3);
    const int by = wg / NXT, bx = wg - by*NXT;
    const int m0 = by*BM, n0 = bx*BN;

    f32x4 acc[4][4] = {};
    const int nk = K >> 6;

    auto STAGE = [&](int t, int buf) {
        const int k0 = t << 6;
        unsigned short* Ab = &Sh[buf*(BM*64)];
        unsigned short* Bb = &Sh[2*BM*64 + buf*(BN*64)];
        #pragma unroll
        for (int p = 0; p < BM/64; ++p) {
            int c = p*512 + tid;
            int row = c >> 3, ch = (c & 7) ^ (row & 7);
            GLOAD_LDS16(&A[(size_t)(m0 + row)*K + k0 + ch*8], &Ab[c*8]);
        }
        #pragma unroll
        for (int p = 0; p < BN/64; ++p) {
            int c = p*512 + tid;
            int row = c >> 3, ch = (c & 7) ^ (row & 7);
            GLOAD_LDS16(&BT[(size_t)(n0 + row)*K + k0 + ch*8], &Bb[c*8]);
        }
    };

    STAGE(0, 0);
    STAGE(1, 1);

    for (int t = 0; t < nk; ++t) {
        const int buf = t & 1;
        const unsigned short* Ab = &Sh[buf*(BM*64)];
        const unsigned short* Bb = &Sh[2*BM*64 + buf*(BN*64)];

        if (t == nk - 1) asm volatile("s_waitcnt vmcnt(0)" ::: "memory");
        else             asm volatile("s_waitcnt vmcnt(6)" ::: "memory");
        __builtin_amdgcn_s_barrier();
        __builtin_amdgcn_sched_barrier(0);           // no ds_read hoists above

        short8 fa[4][2], fb[2][2];

        // ---- phase 0: all m x n-lo
        #pragma unroll
        for (int mi = 0; mi < 4; ++mi)
            #pragma unroll
            for (int kk = 0; kk < 2; ++kk) {
                int row = wm*64 + mi*16 + l16;
                fa[mi][kk] = *(const short8*)&Ab[row*64 + (((kk*4 + quad) ^ (row & 7))*8)];
            }
        #pragma unroll
        for (int ni = 0; ni < 2; ++ni)
            #pragma unroll
            for (int kk = 0; kk < 2; ++kk) {
                int row = wn*64 + ni*16 + l16;
                fb[ni][kk] = *(const short8*)&Bb[row*64 + (((kk*4 + quad) ^ (row & 7))*8)];
            }
        __builtin_amdgcn_s_barrier();
        __builtin_amdgcn_s_setprio(1);
        #pragma unroll
        for (int mi = 0; mi < 4; ++mi)
            #pragma unroll
            for (int ni = 0; ni < 2; ++ni)
                #pragma unroll
                for (int kk = 0; kk < 2; ++kk)
                    acc[mi][ni] = __builtin_amdgcn_mfma_f32_16x16x32_bf16(
                        fa[mi][kk], fb[ni][kk], acc[mi][ni], 0, 0, 0);
        __builtin_amdgcn_s_setprio(0);
        __builtin_amdgcn_s_barrier();

        // ---- phase 1: all m x n-hi
        #pragma unroll
        for (int ni = 0; ni < 2; ++ni)
            #pragma unroll
            for (int kk = 0; kk < 2; ++kk) {
                int row = wn*64 + 32 + ni*16 + l16;
                fb[ni][kk] = *(const short8*)&Bb[row*64 + (((kk*4 + quad) ^ (row & 7))*8)];
            }
        __builtin_amdgcn_s_barrier();
        __builtin_amdgcn_s_setprio(1);
        #pragma unroll
        for (int mi = 0; mi < 4; ++mi)
            #pragma unroll
            for (int ni = 0; ni < 2; ++ni)
                #pragma unroll
                for (int kk = 0; kk < 2; ++kk)
                    acc[mi][2 + ni] = __builtin_amdgcn_mfma_f32_16x16x32_bf16(
                        fa[mi][kk], fb[ni][kk], acc[mi][2 + ni], 0, 0, 0);
        __builtin_amdgcn_s_setprio(0);
        __builtin_amdgcn_s_barrier();                // all buf-t reads consumed

        __builtin_amdgcn_sched_barrier(0);           // STAGE must not hoist above
        if (t + 2 < nk) STAGE(t + 2, buf);           // prefetch 2 tiles ahead
    }

    const int cstride = (MODE == 2) ? 2048 : N;
    #pragma unroll
    for (int ni = 0; ni < 4; ++ni) {
        int n = n0 + wn*64 + ni*16 + l16;
        float bv = bias[n];
        #pragma unroll
        for (int mi = 0; mi < 4; ++mi) {
            #pragma unroll
            for (int r = 0; r < 4; ++r) {
                int m = m0 + wm*64 + mi*16 + quad*4 + r;
                float val = acc[mi][ni][r] + bv;
                if (MODE == 1)
                    ((float*)Cout)[(size_t)m*cstride + n] = val;
                else
                    ((unsigned short*)Cout)[(size_t)m*cstride + n] = f2bf(val);
            }
        }
    }
}

// ---------------- MFMA flash attention: 4-wave block, one q-chunk, grid 1024 ----
// Round-9 post-mortem: grid 1024 + descending-qc backfill worked (123->103us,
// occupancy 19->27.5%, VALUBusy 63%). Now approaching VALU-throughput bound:
// ~600 VALU-equiv vs 16 MFMA per tile per wave. This round, two verified cuts:
//  - T13 defer-max (THR=8, exp2 domain): wave-uniform __any skip of the whole
//    rescale pass (8 exp2 + ~40 mul) when no row max grew by >8 — true for
//    nearly every tile after the first. P bounded by 2^8 (bf16 relative
//    precision is scale-invariant; lsum/O normalize consistently).
//  - v_cvt_pk_bf16_f32 P-pack: 1 cvt_pk + 1 lshr per 2 elems replaces the
//    manual add+lshr (x2) pack; ds_write_b16 stores stay compiler-managed.
// Rest unchanged: K/V LDS dbuf 2-phase pipeline, DPP reductions, XCD pin i&7,
// descending-qc dispatch (long blocks first, short ones backfill).
#define PST 72
__global__ __launch_bounds__(256, 3) void attn_mfma(
    const unsigned short* __restrict__ QK, const unsigned short* __restrict__ VT,
    unsigned short* __restrict__ Y)
{
    // LDS: K dbuf 2x4096 shorts, V dbuf 2x4096 shorts, P 4 waves x 32 x PST
    __shared__ __align__(16) unsigned short Sh[16384 + 4*32*PST];

    const int tid  = threadIdx.x;
    const int lane = tid & 63;
    const int wave = tid >> 6;
    const int quad = lane >> 4, l16 = lane & 15;

    const int i = blockIdx.x;            // 0..1023
    const int xcd = i & 7, j = i >> 3;   // j 0..127
    const int qc = 15 - (j >> 3);        // descending: longest blocks first
    const int u = j & 7;                 // bh-group 0..7
    const int bh2 = xcd + 8*u;
    const int b = bh2 >> 4, h = bh2 & 15;
    const size_t qkbase = (size_t)(b*TT) * 2048;
    const size_t vbase  = (size_t)(bh2*64) * 2048;
    const int qcol = h*64, kcol = 1024 + h*64;
    const float C2 = 0.18033688011112042f;   // (1/sqrt(64)) * log2(e)

    unsigned short* Pw = &Sh[16384 + wave*(32*PST)];

    const int nkt = 2*qc + 2;            // k-tiles for this chunk
    const int q0w = qc*128 + wave*32;    // this wave's q-row base

    // Q fragments straight from global (held for the whole loop)
    short8 aq[2][2];
    #pragma unroll
    for (int mt = 0; mt < 2; ++mt)
        #pragma unroll
        for (int kk = 0; kk < 2; ++kk)
            aq[mt][kk] = *(const short8*)&QK[qkbase + (size_t)(q0w + mt*16 + l16)*2048
                                            + qcol + kk*32 + quad*8];

    f32x4 o[2][4] = {};
    float mold[2][4], lsum[2][4];
    #pragma unroll
    for (int mt = 0; mt < 2; ++mt)
        #pragma unroll
        for (int r = 0; r < 4; ++r) { mold[mt][r] = -3.0e38f; lsum[mt][r] = 0.0f; }

    auto STAGE = [&](int buf, int k0) {
        unsigned short* Kb = &Sh[buf*4096];
        unsigned short* Vb = &Sh[8192 + buf*4096];
        #pragma unroll
        for (int p = 0; p < 2; ++p) {
            int c = p*256 + tid;               // 16B chunk index, linear in lane
            int r = c >> 3;
            int ch = (c & 7) ^ (r & 7);        // source chunk (inverse swizzle)
            GLOAD_LDS16(&QK[qkbase + (size_t)(k0 + r)*2048 + kcol + ch*8], &Kb[c*8]);
        }
        #pragma unroll
        for (int p = 0; p < 2; ++p) {
            int c = p*256 + tid;
            int r = c >> 3;                    // r = head-dim row of VT
            int ch = (c & 7) ^ (r & 7);
            GLOAD_LDS16(&VT[vbase + (size_t)r*2048 + k0 + ch*8], &Vb[c*8]);
        }
    };

    STAGE(0, 0);
    asm volatile("s_waitcnt vmcnt(0)" ::: "memory");
    __builtin_amdgcn_s_barrier();

    int cur = 0;
    for (int t = 0; t < nkt; ++t) {
        const int k0 = t * 64;
        if (t + 1 < nkt) STAGE(cur ^ 1, (t + 1) * 64);   // async prefetch

        if (k0 <= q0w + 31) {                  // wave-uniform causal activity guard
            const unsigned short* Kb = &Sh[cur*4096];
            const unsigned short* Vb = &Sh[8192 + cur*4096];

            // ---- S = Q K^T from LDS (swizzled reads)
            f32x4 s[2][4];
            #pragma unroll
            for (int nt = 0; nt < 4; ++nt) {
                if (k0 + nt*16 <= q0w + 31) {
                    f32x4 z = {};
                    s[0][nt] = z; s[1][nt] = z;
                    #pragma unroll
                    for (int kk = 0; kk < 2; ++kk) {
                        int r = nt*16 + l16;
                        short8 bk = *(const short8*)&Kb[r*64 + (((kk*4 + quad) ^ (r & 7))*8)];
                        s[0][nt] = __builtin_amdgcn_mfma_f32_16x16x32_bf16(aq[0][kk], bk, s[0][nt], 0, 0, 0);
                        s[1][nt] = __builtin_amdgcn_mfma_f32_16x16x32_bf16(aq[1][kk], bk, s[1][nt], 0, 0, 0);
                    }
                } else {
                    #pragma unroll
                    for (int r = 0; r < 4; ++r) { s[0][nt][r] = -3.0e38f; s[1][nt][r] = -3.0e38f; }
                }
            }

            // ---- issue V-frag LDS loads now; latency hides under softmax
            short8 bv[2][4];
            #pragma unroll
            for (int kk = 0; kk < 2; ++kk)
                #pragma unroll
                for (int dt = 0; dt < 4; ++dt) {
                    int r = dt*16 + l16;
                    bv[kk][dt] = *(const short8*)&Vb[r*64 + (((kk*4 + quad) ^ (r & 7))*8)];
                }

            // ---- element causal mask (straddling tiles only)
            if (k0 + 63 > q0w) {
                #pragma unroll
                for (int mt = 0; mt < 2; ++mt)
                    #pragma unroll
                    for (int nt = 0; nt < 4; ++nt)
                        #pragma unroll
                        for (int r = 0; r < 4; ++r) {
                            int kg = k0 + nt*16 + l16;
                            int qg = q0w + mt*16 + quad*4 + r;
                            if (kg > qg) s[mt][nt][r] = -3.0e38f;
                        }
            }

            // ---- online softmax, exp2 domain, defer-max (T13, THR=8)
            float pm[2][4];
            #pragma unroll
            for (int mt = 0; mt < 2; ++mt)
                #pragma unroll
                for (int r = 0; r < 4; ++r) {
                    float rm = fmaxf(fmaxf(s[mt][0][r], s[mt][1][r]),
                                     fmaxf(s[mt][2][r], s[mt][3][r]));
                    pm[mt][r] = red_max16(rm) * C2;
                }
            int need = 0;
            #pragma unroll
            for (int mt = 0; mt < 2; ++mt)
                #pragma unroll
                for (int r = 0; r < 4; ++r)
                    need |= (pm[mt][r] > mold[mt][r] + 8.0f) ? 1 : 0;
            if (__any(need)) {
                #pragma unroll
                for (int mt = 0; mt < 2; ++mt)
                    #pragma unroll
                    for (int r = 0; r < 4; ++r) {
                        float m2 = fmaxf(mold[mt][r], pm[mt][r]);
                        float al = EXP2(mold[mt][r] - m2);
                        mold[mt][r] = m2;
                        lsum[mt][r] *= al;
                        #pragma unroll
                        for (int dt = 0; dt < 4; ++dt)
                            o[mt][dt][r] *= al;
                    }
            }
            float rs[2][4] = {};
            #pragma unroll
            for (int mt = 0; mt < 2; ++mt)
                #pragma unroll
                for (int nt = 0; nt < 4; ++nt)
                    #pragma unroll
                    for (int r = 0; r < 4; ++r) {
                        float p = EXP2(fmaf(s[mt][nt][r], C2, -mold[mt][r]));
                        s[mt][nt][r] = p;
                        rs[mt][r] += p;
                    }
            #pragma unroll
            for (int mt = 0; mt < 2; ++mt)
                #pragma unroll
                for (int r = 0; r < 4; ++r)
                    lsum[mt][r] += red_sum16(rs[mt][r]);

            // ---- P -> LDS via cvt_pk (wave-private buffer; same-wave RAW)
            #pragma unroll
            for (int mt = 0; mt < 2; ++mt)
                #pragma unroll
                for (int r = 0; r < 4; ++r) {
                    int base = (mt*16 + quad*4 + r)*PST + l16;
                    #pragma unroll
                    for (int nt = 0; nt < 4; nt += 2) {
                        uint32_t pkv = cvt_pk_bf16(s[mt][nt][r], s[mt][nt+1][r]);
                        Pw[base + nt*16]       = (unsigned short)pkv;
                        Pw[base + nt*16 + 16]  = (unsigned short)(pkv >> 16);
                    }
                }

            // ---- O += P V
            #pragma unroll
            for (int kk = 0; kk < 2; ++kk) {
                short8 ap0 = *(short8*)&Pw[(     l16)*PST + kk*32 + quad*8];
                short8 ap1 = *(short8*)&Pw[(16 + l16)*PST + kk*32 + quad*8];
                #pragma unroll
                for (int dt = 0; dt < 4; ++dt) {
                    o[0][dt] = __builtin_amdgcn_mfma_f32_16x16x32_bf16(ap0, bv[kk][dt], o[0][dt], 0, 0, 0);
                    o[1][dt] = __builtin_amdgcn_mfma_f32_16x16x32_bf16(ap1, bv[kk][dt], o[1][dt], 0, 0, 0);
                }
            }
        }

        asm volatile("s_waitcnt vmcnt(0)" ::: "memory");  // next-tile stage landed
        __builtin_amdgcn_s_barrier();                     // all waves' stage + reads done
        cur ^= 1;
    }

    // ---- normalize + store (bf16 intermediate Y)
    #pragma unroll
    for (int mt = 0; mt < 2; ++mt)
        #pragma unroll
        for (int r = 0; r < 4; ++r) {
            float inv = 1.0f / lsum[mt][r];
            int tq = q0w + mt*16 + quad*4 + r;
            #pragma unroll
            for (int dt = 0; dt < 4; ++dt)
                Y[((size_t)(b*TT + tq))*DD + h*64 + dt*16 + l16] = f2bf(o[mt][dt][r] * inv);
        }
}

extern "C" void kernel_launch(void* const* d_in, const int* in_sizes, int n_in,
                              void* d_out, int out_size, void* d_ws, size_t ws_size,
                              hipStream_t stream)
{
    const float* x    = (const float*)d_in[0];   // [4,2048,1024] fp32
    // d_in[1] = causal_mask (int32) — causality implemented analytically, unused
    const float* wqkv = (const float*)d_in[2];   // [1024][3072] fp32
    const float* bqkv = (const float*)d_in[3];   // [3072] fp32
    const float* wout = (const float*)d_in[4];   // [1024][1024] fp32
    const float* bout = (const float*)d_in[5];   // [1024] fp32
    float* out = (float*)d_out;                  // [4,2048,1024] fp32

    char* ws = (char*)d_ws;
    unsigned short* Xb    = (unsigned short*)ws;                    // 16 MB
    unsigned short* WqkvT = (unsigned short*)(ws + 16777216);       // 6 MB
    unsigned short* WoutT = (unsigned short*)(ws + 23068672);       // 2 MB
    unsigned short* QK    = (unsigned short*)(ws + 25165824);       // 32 MB [M][2048]
    unsigned short* VTb   = (unsigned short*)(ws + 58720256);       // 16 MB [(bh*64+d)][2048]
    unsigned short* Ybuf  = (unsigned short*)(ws + 75497472);       // 16 MB

    cvt_f32_bf16<<<(M1*KDIM/4 + 255)/256, 256, 0, stream>>>(x, Xb, M1*KDIM/4);
    transpose_f32_bf16<<<dim3(N1/32, KDIM/32), dim3(32, 8), 0, stream>>>(wqkv, WqkvT, KDIM, N1);
    transpose_f32_bf16<<<dim3(DD/32, KDIM/32), dim3(32, 8), 0, stream>>>(wout, WoutT, KDIM, DD);
    gemm8p<2><<<dim3(384), 512, 0, stream>>>(Xb, WqkvT, bqkv, QK, VTb, KDIM, N1, 12);
    attn_mfma<<<dim3(1024), 256, 0, stream>>>(QK, VTb, Ybuf);
    gemm_big<1, 128, 256><<<dim3(256), 512, 0, stream>>>(Ybuf, WoutT, bout, out, nullptr, KDIM, DD, 4);
}